// Round 2
// baseline (279.276 us; speedup 1.0000x reference)
//
#include <hip/hip_runtime.h>
#include <hip/hip_bf16.h>

typedef unsigned short u16;
typedef __attribute__((ext_vector_type(8))) short bf16x8;
typedef __attribute__((ext_vector_type(4))) float f32x4;

#define B_ 8
#define T_ 2048
#define BT_ (B_*T_)
#define DM_ 1024
#define DH_ 64
#define NCH_ 64            // chunks per batch
#define S_ (T_/NCH_)       // 32 steps per chunk
#define STATE_ 896         // leaf 256 + Ws 576 + z 64

__device__ __forceinline__ float b2f(u16 u){ unsigned v=((unsigned)u)<<16; float f; __builtin_memcpy(&f,&v,4); return f; }
__device__ __forceinline__ u16 f2b(float f){ __hip_bfloat16 h=__float2bfloat16(f); u16 u; __builtin_memcpy(&u,&h,2); return u; }

__device__ __forceinline__ float ldin(const void* p, size_t i, int f32){
  return f32 ? ((const float*)p)[i] : b2f(((const u16*)p)[i]);
}
// load 8 consecutive elements as bf16x8 (converting from fp32 if needed)
__device__ __forceinline__ bf16x8 ld8bf(const void* p, size_t i, int f32){
  if (f32){
    f32x4 v0 = *(const f32x4*)((const float*)p + i);
    f32x4 v1 = *(const f32x4*)((const float*)p + i + 4);
    bf16x8 r;
    #pragma unroll
    for (int j=0;j<4;j++){ r[j] = (short)f2b(v0[j]); r[4+j] = (short)f2b(v1[j]); }
    return r;
  }
  return *(const bf16x8*)((const u16*)p + i);
}

// state layout: leaf [0,256): n*16+i*4+j ; Ws: L0@256, L1@384, L2@640, L3@768 ; z@832
__device__ __forceinline__ void decodeWs(int e, int& ia, int& ib){
  if (e<384){ int o=e-256, n=o>>4; ia=n*4+((o>>2)&3); ib=n*4+(o&3); }
  else if (e<640){ int o=e-384, n=o>>6; ia=32+n*8+((o>>3)&7); ib=32+n*8+(o&7); }
  else if (e<768){ int o=e-640, n=o>>6; ia=64+n*8+((o>>3)&7); ib=64+n*8+(o&7); }
  else { int o=e-768; ia=80+((o>>3)&7); ib=80+(o&7); }
}
__device__ __forceinline__ void decode88(int f, int& l, int& n, int& ri){
  if (f<32){ l=0; n=f>>2; ri=f&3; }
  else if (f<64){ l=1; n=(f-32)>>3; ri=f&7; }
  else if (f<80){ l=2; n=(f-64)>>3; ri=f&7; }
  else { l=3; n=0; ri=f&7; }
}

// ---------------- Kernel 0: dtype detection ----------------
__global__ __launch_bounds__(64) void k_detect(const u16* __restrict__ x, int* __restrict__ flag){
  int tid = threadIdx.x;
  int sane = 0;
  for (int i = tid; i < 4096; i += 64){
    u16 u = x[i];
    int e = (u >> 7) & 0xFF;
    if ((u & 0x7FFF) == 0 || (e >= 100 && e <= 140)) sane++;
  }
  #pragma unroll
  for (int o = 32; o > 0; o >>= 1) sane += __shfl_down(sane, o);
  if (tid == 0) flag[0] = (sane < 3600) ? 1 : 0;
}

// ---------------- Kernel 0c: weight/basis -> MFMA B-fragment layout (bf16) ------
// QKV frags: e=((m*32+ks)*4+nt)*64+lane ; elem j = W_m[ks*32+(lane>>4)*8+j][nt*16+(lane&15)]
// Wo frags:  eo=(ks*64+nt)*64+lane      ; elem j = Wo[...][...]
// Prep frags: pe=((mat*2+ks)*6+nt)*64+lane over 64x96 matrices {Mu(UL),Mv(VR),Mlx(VL)}
__global__ __launch_bounds__(256) void k_wfrag(
    const void* __restrict__ Wq, const void* __restrict__ Wk, const void* __restrict__ Wv,
    const void* __restrict__ Wo,
    const void* __restrict__ UL0, const void* __restrict__ UL1, const void* __restrict__ UL2, const void* __restrict__ UL3,
    const void* __restrict__ VR0, const void* __restrict__ VR1, const void* __restrict__ VR2, const void* __restrict__ VR3,
    const void* __restrict__ VL0, const void* __restrict__ VL1, const void* __restrict__ VL2, const void* __restrict__ VL3,
    u16* __restrict__ WF, u16* __restrict__ WoF, u16* __restrict__ PF,
    const int* __restrict__ fl)
{
  const int f32 = fl[0];
  int e = blockIdx.x*256 + threadIdx.x;
  if (e < 24576){
    int m = e >> 13;
    int rem = e & 8191;
    int ks = rem >> 8;
    int nt = (rem >> 6) & 3;
    int lane = rem & 63;
    const void* W = (m==0)?Wq:((m==1)?Wk:Wv);
    int kr = ks*32 + (lane>>4)*8;
    int col = nt*16 + (lane&15);
    u16 o[8];
    #pragma unroll
    for (int j=0;j<8;j++) o[j] = f2b(ldin(W, (size_t)(kr+j)*DH_ + col, f32));
    u16* dst = WF + (size_t)e*8;
    #pragma unroll
    for (int j=0;j<8;j++) dst[j] = o[j];
  } else if (e < 32768){
    int eo = e - 24576;
    int ks = eo >> 12;
    int nt = (eo >> 6) & 63;
    int lane = eo & 63;
    int kr = ks*32 + (lane>>4)*8;
    int col = nt*16 + (lane&15);
    u16 o[8];
    #pragma unroll
    for (int j=0;j<8;j++) o[j] = f2b(ldin(Wo, (size_t)(kr+j)*DM_ + col, f32));
    u16* dst = WoF + (size_t)eo*8;
    #pragma unroll
    for (int j=0;j<8;j++) dst[j] = o[j];
  } else if (e < 35072){
    int pe = e - 32768;         // 0..2303
    int lane = pe & 63;
    int nt = (pe >> 6) % 6;
    int mk = pe / 384;          // mat*2+ks
    int ks = mk & 1, mat = mk >> 1;
    int col = nt*16 + (lane&15);
    int dbase = ks*32 + (lane>>4)*8;
    const int BSl[4]={4,8,16,32}; const int Rl[4]={4,8,8,8};
    u16 o[8];
    #pragma unroll
    for (int j=0;j<8;j++){
      float val = 0.f;
      if (col < 88){
        int l,n,ri; decode88(col,l,n,ri);
        int bs=BSl[l], r=Rl[l];
        int lo = n*2*bs + ((mat==1)?bs:0);
        int d = dbase + j;
        if (d >= lo && d < lo+bs){
          const void* Up;
          if (mat==0)      Up = (l==0)?UL0:(l==1)?UL1:(l==2)?UL2:UL3;
          else if (mat==1) Up = (l==0)?VR0:(l==1)?VR1:(l==2)?VR2:VR3;
          else             Up = (l==0)?VL0:(l==1)?VL1:(l==2)?VL2:VL3;
          val = ldin(Up, (size_t)(d-lo)*r + ri, f32);
        }
      }
      o[j] = f2b(val);
    }
    u16* dst = PF + (size_t)pe*8;
    #pragma unroll
    for (int j=0;j<8;j++) dst[j] = o[j];
  }
}

// ---------------- Kernel 1: QKV projection — 4-way K-split, 24 waves/CU ----------
// grid (512, 3): blockIdx.y selects matrix (q/k/v); 4 waves each do 8 K-steps,
// combined via 24 KB LDS. 6144 waves (~24/CU) vs round-1's 3072 (~12/CU).
__global__ __launch_bounds__(256) void k_proj4(
    const void* __restrict__ x, const u16* __restrict__ WF,
    float* __restrict__ oq, float* __restrict__ ok_, float* __restrict__ ov,
    u16* __restrict__ qb16, u16* __restrict__ kb16, u16* __restrict__ vb16,
    const int* __restrict__ fl)
{
  __shared__ f32x4 red[3][8][64];   // 24 KB: waves 1..3 partial accumulators
  const int f32 = fl[0];
  const int m = blockIdx.y;
  const int rows0 = blockIdx.x*32;
  const int wv = threadIdx.x>>6;
  const int lane = threadIdx.x&63;
  const int quad = lane>>4, l16 = lane&15;
  const size_t rowA0 = (size_t)(rows0 + l16)*DM_;
  const size_t rowA1 = (size_t)(rows0 + 16 + l16)*DM_;

  f32x4 acc[8];
  #pragma unroll
  for (int i=0;i<8;i++) acc[i] = (f32x4){0.f,0.f,0.f,0.f};

  const int ks0 = wv*8;
  #pragma unroll 4
  for (int kk=0;kk<8;kk++){
    int ks = ks0 + kk;
    int ko = ks*32 + quad*8;
    bf16x8 a0 = ld8bf(x, rowA0 + ko, f32);
    bf16x8 a1 = ld8bf(x, rowA1 + ko, f32);
    #pragma unroll
    for (int nt=0;nt<4;nt++){
      bf16x8 b = *(const bf16x8*)(WF + ((size_t)((m*32+ks)*4+nt)*64 + lane)*8);
      acc[nt]   = __builtin_amdgcn_mfma_f32_16x16x32_bf16(a0,b,acc[nt],0,0,0);
      acc[4+nt] = __builtin_amdgcn_mfma_f32_16x16x32_bf16(a1,b,acc[4+nt],0,0,0);
    }
  }

  if (wv>0){
    #pragma unroll
    for (int i=0;i<8;i++) red[wv-1][i][lane] = acc[i];
  }
  __syncthreads();
  if (wv==0){
    #pragma unroll
    for (int i=0;i<8;i++){
      f32x4 r0 = red[0][i][lane];
      f32x4 r1 = red[1][i][lane];
      f32x4 r2 = red[2][i][lane];
      acc[i][0]+=r0[0]+r1[0]+r2[0]; acc[i][1]+=r0[1]+r1[1]+r2[1];
      acc[i][2]+=r0[2]+r1[2]+r2[2]; acc[i][3]+=r0[3]+r1[3]+r2[3];
    }
    float* __restrict__ outp = (m==0)?oq:((m==1)?ok_:ov);
    u16* __restrict__ outb = (m==0)?qb16:((m==1)?kb16:vb16);
    #pragma unroll
    for (int sp=0;sp<2;sp++){
      #pragma unroll
      for (int nt=0;nt<4;nt++){
        #pragma unroll
        for (int i=0;i<4;i++){
          int row = rows0 + sp*16 + quad*4 + i;
          int col = nt*16 + l16;
          float val = acc[sp*4+nt][i];
          if (m<2) val = (val>0.f)? (val+1.f) : expf(val);  // elu1
          outp[(size_t)row*DH_ + col] = val;
          outb[(size_t)row*DH_ + col] = f2b(val);
        }
      }
    }
  }
}

// ---------------- Kernel 2: basis projections via MFMA — per-matrix split --------
// grid (1024, 4): blockIdx.y selects output {uL,vR,vrx,vlx}. 4096 waves (~16/CU)
// vs old 1024 (~4/CU, 1/SIMD — round-0 disease).
__global__ __launch_bounds__(64) void k_prep3(
    const u16* __restrict__ qb16, const u16* __restrict__ kb16, const u16* __restrict__ vb16,
    const u16* __restrict__ PF,
    float* __restrict__ uLa, float* __restrict__ vRa, float* __restrict__ vrxa, float* __restrict__ vlxa)
{
  const int m = blockIdx.y;          // 0:uL=K@Mu 1:vR=V@Mv 2:vrx=Q@Mv 3:vlx=Q@Mlx
  const int rows0 = blockIdx.x*16;
  const int lane = threadIdx.x;
  const int quad = lane>>4, l16 = lane&15;

  const u16* __restrict__ src = (m==0)?kb16:((m==1)?vb16:qb16);
  const int mat = (m==0)?0:((m==3)?2:1);   // PF matrix index {Mu,Mv,Mlx}

  bf16x8 a[2];
  #pragma unroll
  for (int ks=0;ks<2;ks++){
    size_t off = (size_t)(rows0 + l16)*DH_ + ks*32 + quad*8;
    a[ks] = *(const bf16x8*)(src + off);
  }
  f32x4 acc[6];
  #pragma unroll
  for (int nt=0;nt<6;nt++) acc[nt] = (f32x4){0.f,0.f,0.f,0.f};

  #pragma unroll
  for (int ks=0;ks<2;ks++){
    #pragma unroll
    for (int nt=0;nt<6;nt++){
      bf16x8 b = *(const bf16x8*)(PF + ((size_t)((mat*2+ks)*6+nt)*64 + lane)*8);
      acc[nt] = __builtin_amdgcn_mfma_f32_16x16x32_bf16(a[ks], b, acc[nt],0,0,0);
    }
  }
  float* __restrict__ dst = (m==0)?uLa:(m==1)?vRa:(m==2)?vrxa:vlxa;
  #pragma unroll
  for (int nt=0;nt<6;nt++){
    int col = nt*16 + l16;
    if (col < 88){
      #pragma unroll
      for (int i=0;i<4;i++){
        int row = rows0 + quad*4 + i;
        dst[(size_t)row*88 + col] = acc[nt][i];
      }
    }
  }
}

// ---------------- Kernel 3: per-chunk state sums ----------------
__global__ __launch_bounds__(256) void k_chunksum(
    const float* __restrict__ gk, const float* __restrict__ gv,
    const float* __restrict__ uLa, const float* __restrict__ vRa,
    float* __restrict__ SL)
{
  const int bid = blockIdx.x;
  const int b = bid/NCH_, c = bid%NCH_;
  const size_t base64 = (size_t)(b*T_ + c*S_)*64;
  const size_t base88 = (size_t)(b*T_ + c*S_)*88;
  for (int p=0;p<4;p++){
    int e = threadIdx.x + p*256;
    if (e>=STATE_) break;
    float acc=0.f;
    if (e < 256){
      int n=e>>4;
      const float* A = gk + base64 + n*4 + ((e>>2)&3);
      const float* Bp = gv + base64 + n*4 + (e&3);
      for (int s=0;s<S_;s++) acc += A[s*64]*Bp[s*64];
    } else if (e < 832){
      int ia, ib; decodeWs(e, ia, ib);
      const float* A = uLa + base88 + ia;
      const float* Bp = vRa + base88 + ib;
      for (int s=0;s<S_;s++) acc += A[s*88]*Bp[s*88];
    } else {
      const float* A = gk + base64 + (e-832);
      for (int s=0;s<S_;s++) acc += A[s*64];
    }
    SL[(size_t)bid*STATE_ + e] = acc;
  }
}

// ---------------- Kernel 4: exclusive prefix over chunks ----------------
__global__ __launch_bounds__(256) void k_prefix(const float* __restrict__ SL, float* __restrict__ SP){
  const int b = blockIdx.x;
  for (int p=0;p<4;p++){
    int e = threadIdx.x + p*256;
    if (e>=STATE_) break;
    float run=0.f;
    for (int c=0;c<NCH_;c++){
      size_t idx = ((size_t)(b*NCH_+c))*STATE_ + e;
      SP[idx] = run; run += SL[idx];
    }
  }
}

// ---------------- Kernel 5: parallel intra-chunk ----------------
__global__ __launch_bounds__(256) void k_intra(
    const float* __restrict__ gq, const float* __restrict__ gk, const float* __restrict__ gv,
    const float* __restrict__ uLa, const float* __restrict__ vRa,
    const float* __restrict__ vrxa, const float* __restrict__ vlxa,
    const float* __restrict__ SP,
    const void* __restrict__ UL0, const void* __restrict__ UL1, const void* __restrict__ UL2, const void* __restrict__ UL3,
    const void* __restrict__ UR0, const void* __restrict__ UR1, const void* __restrict__ UR2, const void* __restrict__ UR3,
    u16* __restrict__ Yb, const int* __restrict__ fl)
{
  __shared__ float kS[S_*64];
  __shared__ float vS[S_*64];
  __shared__ float uvS[S_*176];
  __shared__ float st0[STATE_];
  __shared__ float ULs[464], URs[464];
  const int f32 = fl[0];
  const int tid = threadIdx.x;
  const int bid = blockIdx.x;
  const int b = bid/NCH_, c = bid%NCH_;
  const int row0 = b*T_ + c*S_;

  const size_t r64 = (size_t)row0*64;
  for (int i=tid;i<S_*64;i+=256){ kS[i]=gk[r64+i]; vS[i]=gv[r64+i]; }
  const size_t r88 = (size_t)row0*88;
  for (int i=tid;i<S_*88;i+=256){
    int s=i/88, f=i-s*88;
    uvS[s*176+f]    = uLa[r88+i];
    uvS[s*176+88+f] = vRa[r88+i];
  }
  for (int e=tid;e<STATE_;e+=256) st0[e] = SP[(size_t)bid*STATE_+e];
  for (int e=tid;e<464;e+=256){
    int l, idx;
    if (e<16){ l=0; idx=e; } else if (e<80){ l=1; idx=e-16; }
    else if (e<208){ l=2; idx=e-80; } else { l=3; idx=e-208; }
    const void* ul = (l==0)?UL0:(l==1)?UL1:(l==2)?UL2:UL3;
    const void* ur = (l==0)?UR0:(l==1)?UR1:(l==2)?UR2:UR3;
    ULs[e] = ldin(ul, idx, f32); URs[e] = ldin(ur, idx, f32);
  }
  __syncthreads();

  const int w = tid>>6, lane = tid&63, tl = lane>>3, g = lane&7;
  const int t = w*8 + tl;
  const int n1 = g>>1, ri1 = (g&1)*4;
  const int n2 = g>>2, ri2 = (g&3)*2;
  const size_t row = (size_t)(row0 + t);

  float qr[8];
  { const float* qp = gq + row*64 + g*8;
    *(f32x4*)&qr[0] = *(const f32x4*)qp; *(f32x4*)&qr[4] = *(const f32x4*)(qp+4); }
  float rxL0[4], lxL0[4], rxL1[8], lxL1[8], rxL2[8], lxL2[8], rxL3[8], lxL3[8];
  { const float* rp = vrxa + row*88; const float* lp = vlxa + row*88;
    *(f32x4*)&rxL0[0] = *(const f32x4*)(rp + 4*g);
    *(f32x4*)&lxL0[0] = *(const f32x4*)(lp + 4*g);
    *(f32x4*)&rxL1[0] = *(const f32x4*)(rp + 32 + n1*8); *(f32x4*)&rxL1[4] = *(const f32x4*)(rp + 36 + n1*8);
    *(f32x4*)&lxL1[0] = *(const f32x4*)(lp + 32 + n1*8); *(f32x4*)&lxL1[4] = *(const f32x4*)(lp + 36 + n1*8);
    *(f32x4*)&rxL2[0] = *(const f32x4*)(rp + 64 + n2*8); *(f32x4*)&rxL2[4] = *(const f32x4*)(rp + 68 + n2*8);
    *(f32x4*)&lxL2[0] = *(const f32x4*)(lp + 64 + n2*8); *(f32x4*)&lxL2[4] = *(const f32x4*)(lp + 68 + n2*8);
    *(f32x4*)&rxL3[0] = *(const f32x4*)(rp + 80); *(f32x4*)&rxL3[4] = *(const f32x4*)(rp + 84);
    *(f32x4*)&lxL3[0] = *(const f32x4*)(lp + 80); *(f32x4*)&lxL3[4] = *(const f32x4*)(lp + 84); }

  float yacc[8], den = 0.f;
  #pragma unroll
  for (int cc=0;cc<8;cc++){
    int n = 2*g + (cc>>2);
    const float* m = &st0[n*16 + (cc&3)*4];
    const float* qp = &qr[(cc>>2)*4];
    yacc[cc] = m[0]*qp[0]+m[1]*qp[1]+m[2]*qp[2]+m[3]*qp[3];
    den += st0[832 + g*8 + cc]*qr[cc];
  }
  float gtL0[4], gbL0[4], gtL1[4], gbL1[4], gtL2[2], gbL2[2], gtL3, gbL3;
  #pragma unroll
  for (int cc=0;cc<4;cc++){
    const float* m = &st0[256 + g*16 + cc*4];
    gtL0[cc] = m[0]*rxL0[0]+m[1]*rxL0[1]+m[2]*rxL0[2]+m[3]*rxL0[3];
    float s2 = 0.f;
    #pragma unroll
    for (int j=0;j<4;j++) s2 += st0[256 + g*16 + j*4 + cc]*lxL0[j];
    gbL0[cc] = s2;
  }
  #pragma unroll
  for (int cc=0;cc<4;cc++){
    int ri = ri1 + cc;
    float s1=0.f, s2=0.f;
    #pragma unroll
    for (int j=0;j<8;j++){
      s1 += st0[384 + n1*64 + ri*8 + j]*rxL1[j];
      s2 += st0[384 + n1*64 + j*8 + ri]*lxL1[j];
    }
    gtL1[cc]=s1; gbL1[cc]=s2;
  }
  #pragma unroll
  for (int cc=0;cc<2;cc++){
    int ri = ri2 + cc;
    float s1=0.f, s2=0.f;
    #pragma unroll
    for (int j=0;j<8;j++){
      s1 += st0[640 + n2*64 + ri*8 + j]*rxL2[j];
      s2 += st0[640 + n2*64 + j*8 + ri]*lxL2[j];
    }
    gtL2[cc]=s1; gbL2[cc]=s2;
  }
  { float s1=0.f, s2=0.f;
    #pragma unroll
    for (int j=0;j<8;j++){
      s1 += st0[768 + g*8 + j]*rxL3[j];
      s2 += st0[768 + j*8 + g]*lxL3[j];
    }
    gtL3=s1; gbL3=s2; }

  const int smax = w*8 + 8;
  for (int s=0; s<smax; s++){
    const float* ks_ = &kS[s*64 + g*8];
    const float* vs_ = &vS[s*64 + g*8];
    const float* uL_ = &uvS[s*176];
    const float* vR_ = &uvS[s*176 + 88];
    float dv0 = vs_[0]*qr[0]+vs_[1]*qr[1]+vs_[2]*qr[2]+vs_[3]*qr[3];
    float dv1 = vs_[4]*qr[4]+vs_[5]*qr[5]+vs_[6]*qr[6]+vs_[7]*qr[7];
    float dn = 0.f;
    #pragma unroll
    for (int cc=0;cc<8;cc++) dn += ks_[cc]*qr[cc];
    float d1L0=0.f,d2L0=0.f;
    #pragma unroll
    for (int j=0;j<4;j++){ d1L0 += vR_[4*g+j]*rxL0[j]; d2L0 += uL_[4*g+j]*lxL0[j]; }
    float d1L1=0.f,d2L1=0.f;
    #pragma unroll
    for (int j=0;j<8;j++){ d1L1 += vR_[32+n1*8+j]*rxL1[j]; d2L1 += uL_[32+n1*8+j]*lxL1[j]; }
    float d1L2=0.f,d2L2=0.f;
    #pragma unroll
    for (int j=0;j<8;j++){ d1L2 += vR_[64+n2*8+j]*rxL2[j]; d2L2 += uL_[64+n2*8+j]*lxL2[j]; }
    float d1L3=0.f,d2L3=0.f;
    #pragma unroll
    for (int j=0;j<8;j++){ d1L3 += vR_[80+j]*rxL3[j]; d2L3 += uL_[80+j]*lxL3[j]; }
    if (s<=t){
      den += dn;
      #pragma unroll
      for (int cc=0;cc<8;cc++) yacc[cc] += ks_[cc]*((cc<4)?dv0:dv1);
      #pragma unroll
      for (int cc=0;cc<4;cc++){
        gtL0[cc] += uL_[4*g+cc]*d1L0;          gbL0[cc] += vR_[4*g+cc]*d2L0;
        gtL1[cc] += uL_[32+n1*8+ri1+cc]*d1L1;  gbL1[cc] += vR_[32+n1*8+ri1+cc]*d2L1;
      }
      #pragma unroll
      for (int cc=0;cc<2;cc++){
        gtL2[cc] += uL_[64+n2*8+ri2+cc]*d1L2;  gbL2[cc] += vR_[64+n2*8+ri2+cc]*d2L2;
      }
      gtL3 += uL_[80+g]*d1L3;  gbL3 += vR_[80+g]*d2L3;
    }
  }
  __syncthreads();

  { float* gr = &uvS[t*176];
    #pragma unroll
    for (int cc=0;cc<4;cc++){
      gr[4*g+cc] = gtL0[cc];                 gr[88+4*g+cc] = gbL0[cc];
      gr[32+n1*8+ri1+cc] = gtL1[cc];         gr[88+32+n1*8+ri1+cc] = gbL1[cc];
    }
    #pragma unroll
    for (int cc=0;cc<2;cc++){
      gr[64+n2*8+ri2+cc] = gtL2[cc];         gr[88+64+n2*8+ri2+cc] = gbL2[cc];
    }
    gr[80+g] = gtL3;  gr[88+80+g] = gbL3;
  }
  __syncthreads();

  den += __shfl_xor(den,1); den += __shfl_xor(den,2); den += __shfl_xor(den,4);
  float inv = 1.f / fmaxf(den, 1e-6f);
  const float* gr = &uvS[t*176];
  float yout[8];
  #pragma unroll
  for (int cc=0;cc<8;cc++){
    int j = g*8 + cc;
    float y = yacc[cc];
    if (cc<4){
      #pragma unroll
      for (int rr=0;rr<4;rr++) y += ULs[cc*4+rr]*gr[g*4+rr];
    } else {
      #pragma unroll
      for (int rr=0;rr<4;rr++) y += URs[(cc-4)*4+rr]*gr[88+g*4+rr];
    }
    { int seg=j>>4, pos=j&15;
      if (pos<8){
        #pragma unroll
        for (int rr=0;rr<8;rr++) y += ULs[16+pos*8+rr]*gr[32+seg*8+rr];
      } else {
        #pragma unroll
        for (int rr=0;rr<8;rr++) y += URs[16+(pos-8)*8+rr]*gr[88+32+seg*8+rr];
      } }
    { int seg=j>>5, pos=j&31;
      if (pos<16){
        #pragma unroll
        for (int rr=0;rr<8;rr++) y += ULs[80+pos*8+rr]*gr[64+seg*8+rr];
      } else {
        #pragma unroll
        for (int rr=0;rr<8;rr++) y += URs[80+(pos-16)*8+rr]*gr[88+64+seg*8+rr];
      } }
    { int pos=j;
      if (pos<32){
        #pragma unroll
        for (int rr=0;rr<8;rr++) y += ULs[208+pos*8+rr]*gr[80+rr];
      } else {
        #pragma unroll
        for (int rr=0;rr<8;rr++) y += URs[208+(pos-32)*8+rr]*gr[88+80+rr];
      } }
    yout[cc] = y*inv;
  }
  u16* yp = Yb + row*64 + g*8;
  ushort4 o1, o2;
  o1.x=f2b(yout[0]); o1.y=f2b(yout[1]); o1.z=f2b(yout[2]); o1.w=f2b(yout[3]);
  o2.x=f2b(yout[4]); o2.y=f2b(yout[5]); o2.z=f2b(yout[6]); o2.w=f2b(yout[7]);
  *(ushort4*)yp = o1;
  *(ushort4*)(yp+4) = o2;
}

// ---------------- Kernel 6: output projection — no LDS, no barriers ----------------
__global__ __launch_bounds__(64) void k_outproj2(
    const u16* __restrict__ Yb, const u16* __restrict__ WoF, void* __restrict__ outv,
    const int* __restrict__ fl)
{
  const int f32 = fl[0];
  const int rows0 = blockIdx.x*32;
  const int nt0 = blockIdx.y*16;
  const int lane = threadIdx.x;
  const int quad = lane>>4, l16 = lane&15;

  f32x4 acc[32];
  #pragma unroll
  for (int i=0;i<32;i++) acc[i] = (f32x4){0.f,0.f,0.f,0.f};

  #pragma unroll
  for (int ks=0;ks<2;ks++){
    int ko = ks*32 + quad*8;
    bf16x8 a0 = *(const bf16x8*)(Yb + (size_t)(rows0 + l16)*DH_ + ko);
    bf16x8 a1 = *(const bf16x8*)(Yb + (size_t)(rows0 + 16 + l16)*DH_ + ko);
    #pragma unroll
    for (int nt=0;nt<16;nt++){
      bf16x8 b = *(const bf16x8*)(WoF + ((size_t)(ks*64 + nt0 + nt)*64 + lane)*8);
      acc[nt]    = __builtin_amdgcn_mfma_f32_16x16x32_bf16(a0,b,acc[nt],0,0,0);
      acc[16+nt] = __builtin_amdgcn_mfma_f32_16x16x32_bf16(a1,b,acc[16+nt],0,0,0);
    }
  }
  #pragma unroll
  for (int sp=0;sp<2;sp++){
    #pragma unroll
    for (int nt=0;nt<16;nt++){
      #pragma unroll
      for (int i=0;i<4;i++){
        int row = rows0 + sp*16 + quad*4 + i;
        int col = (nt0+nt)*16 + l16;
        size_t idx = (size_t)row*DM_ + col;
        float v = acc[sp*16+nt][i];
        if (f32) ((float*)outv)[idx] = v;
        else ((u16*)outv)[idx] = f2b(v);
      }
    }
  }
}

extern "C" void kernel_launch(void* const* d_in, const int* in_sizes, int n_in,
                              void* d_out, int out_size, void* d_ws, size_t ws_size,
                              hipStream_t stream) {
  const void* x  = d_in[0];
  const void* Wq = d_in[1];
  const void* Wk = d_in[2];
  const void* Wv = d_in[3];
  const void* Wo = d_in[4];
  const void* UL[4] = {d_in[5],d_in[6],d_in[7],d_in[8]};
  const void* VR[4] = {d_in[9],d_in[10],d_in[11],d_in[12]};
  const void* UR[4] = {d_in[13],d_in[14],d_in[15],d_in[16]};
  const void* VL[4] = {d_in[17],d_in[18],d_in[19],d_in[20]};

  int* flag = (int*)d_ws;
  float* ws = (float*)d_ws + 16;
  float* q    = ws;
  float* kf   = q    + (size_t)BT_*64;
  float* vf   = kf   + (size_t)BT_*64;
  float* uLa  = vf   + (size_t)BT_*64;
  float* vRa  = uLa  + (size_t)BT_*88;
  float* vrxa = vRa  + (size_t)BT_*88;
  float* vlxa = vrxa + (size_t)BT_*88;
  float* SL   = vlxa + (size_t)BT_*88;
  float* SP   = SL   + (size_t)B_*NCH_*STATE_;
  u16*   Yb   = (u16*)(SP + (size_t)B_*NCH_*STATE_);
  u16*   WF   = Yb  + (size_t)BT_*64;
  u16*   WoF  = WF  + (size_t)196608;
  u16*   PF   = WoF + (size_t)65536;
  u16*   qb16 = PF  + (size_t)18432;
  u16*   kb16 = qb16 + (size_t)BT_*64;
  u16*   vb16 = kb16 + (size_t)BT_*64;

  k_detect<<<1, 64, 0, stream>>>((const u16*)x, flag);
  k_wfrag<<<137, 256, 0, stream>>>(Wq, Wk, Wv, Wo,
      UL[0],UL[1],UL[2],UL[3], VR[0],VR[1],VR[2],VR[3], VL[0],VL[1],VL[2],VL[3],
      WF, WoF, PF, flag);
  k_proj4<<<dim3(512, 3), 256, 0, stream>>>(x, WF, q, kf, vf, qb16, kb16, vb16, flag);
  k_prep3<<<dim3(BT_/16, 4), 64, 0, stream>>>(qb16, kb16, vb16, PF, uLa, vRa, vrxa, vlxa);
  k_chunksum<<<B_*NCH_, 256, 0, stream>>>(kf, vf, uLa, vRa, SL);
  k_prefix<<<B_, 256, 0, stream>>>(SL, SP);
  k_intra<<<B_*NCH_, 256, 0, stream>>>(q, kf, vf, uLa, vRa, vrxa, vlxa, SP,
      UL[0],UL[1],UL[2],UL[3], UR[0],UR[1],UR[2],UR[3], Yb, flag);
  k_outproj2<<<dim3(512, 4), 64, 0, stream>>>(Yb, WoF, d_out, flag);
}

// Round 3
// 278.180 us; speedup vs baseline: 1.0039x; 1.0039x over previous
//
#include <hip/hip_runtime.h>
#include <hip/hip_bf16.h>

typedef unsigned short u16;
typedef __attribute__((ext_vector_type(8))) short bf16x8;
typedef __attribute__((ext_vector_type(4))) float f32x4;

#define B_ 8
#define T_ 2048
#define BT_ (B_*T_)
#define DM_ 1024
#define DH_ 64
#define NCH_ 64            // chunks per batch
#define S_ (T_/NCH_)       // 32 steps per chunk
#define STATE_ 896         // leaf 256 + Ws 576 + z 64

__device__ __forceinline__ float b2f(u16 u){ unsigned v=((unsigned)u)<<16; float f; __builtin_memcpy(&f,&v,4); return f; }
__device__ __forceinline__ u16 f2b(float f){ __hip_bfloat16 h=__float2bfloat16(f); u16 u; __builtin_memcpy(&u,&h,2); return u; }

__device__ __forceinline__ float ldin(const void* p, size_t i, int f32){
  return f32 ? ((const float*)p)[i] : b2f(((const u16*)p)[i]);
}
// load 8 consecutive elements as bf16x8 (converting from fp32 if needed)
__device__ __forceinline__ bf16x8 ld8bf(const void* p, size_t i, int f32){
  if (f32){
    f32x4 v0 = *(const f32x4*)((const float*)p + i);
    f32x4 v1 = *(const f32x4*)((const float*)p + i + 4);
    bf16x8 r;
    #pragma unroll
    for (int j=0;j<4;j++){ r[j] = (short)f2b(v0[j]); r[4+j] = (short)f2b(v1[j]); }
    return r;
  }
  return *(const bf16x8*)((const u16*)p + i);
}

// state layout: leaf [0,256): n*16+i*4+j ; Ws: L0@256, L1@384, L2@640, L3@768 ; z@832
__device__ __forceinline__ void decodeWs(int e, int& ia, int& ib){
  if (e<384){ int o=e-256, n=o>>4; ia=n*4+((o>>2)&3); ib=n*4+(o&3); }
  else if (e<640){ int o=e-384, n=o>>6; ia=32+n*8+((o>>3)&7); ib=32+n*8+(o&7); }
  else if (e<768){ int o=e-640, n=o>>6; ia=64+n*8+((o>>3)&7); ib=64+n*8+(o&7); }
  else { int o=e-768; ia=80+((o>>3)&7); ib=80+(o&7); }
}
__device__ __forceinline__ void decode88(int f, int& l, int& n, int& ri){
  if (f<32){ l=0; n=f>>2; ri=f&3; }
  else if (f<64){ l=1; n=(f-32)>>3; ri=f&7; }
  else if (f<80){ l=2; n=(f-64)>>3; ri=f&7; }
  else { l=3; n=0; ri=f&7; }
}

// ---------------- Kernel 0: dtype detection ----------------
__global__ __launch_bounds__(64) void k_detect(const u16* __restrict__ x, int* __restrict__ flag){
  int tid = threadIdx.x;
  int sane = 0;
  for (int i = tid; i < 4096; i += 64){
    u16 u = x[i];
    int e = (u >> 7) & 0xFF;
    if ((u & 0x7FFF) == 0 || (e >= 100 && e <= 140)) sane++;
  }
  #pragma unroll
  for (int o = 32; o > 0; o >>= 1) sane += __shfl_down(sane, o);
  if (tid == 0) flag[0] = (sane < 3600) ? 1 : 0;
}

// ---------------- Kernel 0c: weight/basis -> MFMA B-fragment layout (bf16) ------
__global__ __launch_bounds__(256) void k_wfrag(
    const void* __restrict__ Wq, const void* __restrict__ Wk, const void* __restrict__ Wv,
    const void* __restrict__ Wo,
    const void* __restrict__ UL0, const void* __restrict__ UL1, const void* __restrict__ UL2, const void* __restrict__ UL3,
    const void* __restrict__ VR0, const void* __restrict__ VR1, const void* __restrict__ VR2, const void* __restrict__ VR3,
    const void* __restrict__ VL0, const void* __restrict__ VL1, const void* __restrict__ VL2, const void* __restrict__ VL3,
    u16* __restrict__ WF, u16* __restrict__ WoF, u16* __restrict__ PF,
    const int* __restrict__ fl)
{
  const int f32 = fl[0];
  int e = blockIdx.x*256 + threadIdx.x;
  if (e < 24576){
    int m = e >> 13;
    int rem = e & 8191;
    int ks = rem >> 8;
    int nt = (rem >> 6) & 3;
    int lane = rem & 63;
    const void* W = (m==0)?Wq:((m==1)?Wk:Wv);
    int kr = ks*32 + (lane>>4)*8;
    int col = nt*16 + (lane&15);
    u16 o[8];
    #pragma unroll
    for (int j=0;j<8;j++) o[j] = f2b(ldin(W, (size_t)(kr+j)*DH_ + col, f32));
    u16* dst = WF + (size_t)e*8;
    #pragma unroll
    for (int j=0;j<8;j++) dst[j] = o[j];
  } else if (e < 32768){
    int eo = e - 24576;
    int ks = eo >> 12;
    int nt = (eo >> 6) & 63;
    int lane = eo & 63;
    int kr = ks*32 + (lane>>4)*8;
    int col = nt*16 + (lane&15);
    u16 o[8];
    #pragma unroll
    for (int j=0;j<8;j++) o[j] = f2b(ldin(Wo, (size_t)(kr+j)*DM_ + col, f32));
    u16* dst = WoF + (size_t)eo*8;
    #pragma unroll
    for (int j=0;j<8;j++) dst[j] = o[j];
  } else if (e < 35072){
    int pe = e - 32768;         // 0..2303
    int lane = pe & 63;
    int nt = (pe >> 6) % 6;
    int mk = pe / 384;          // mat*2+ks
    int ks = mk & 1, mat = mk >> 1;
    int col = nt*16 + (lane&15);
    int dbase = ks*32 + (lane>>4)*8;
    const int BSl[4]={4,8,16,32}; const int Rl[4]={4,8,8,8};
    u16 o[8];
    #pragma unroll
    for (int j=0;j<8;j++){
      float val = 0.f;
      if (col < 88){
        int l,n,ri; decode88(col,l,n,ri);
        int bs=BSl[l], r=Rl[l];
        int lo = n*2*bs + ((mat==1)?bs:0);
        int d = dbase + j;
        if (d >= lo && d < lo+bs){
          const void* Up;
          if (mat==0)      Up = (l==0)?UL0:(l==1)?UL1:(l==2)?UL2:UL3;
          else if (mat==1) Up = (l==0)?VR0:(l==1)?VR1:(l==2)?VR2:VR3;
          else             Up = (l==0)?VL0:(l==1)?VL1:(l==2)?VL2:VL3;
          val = ldin(Up, (size_t)(d-lo)*r + ri, f32);
        }
      }
      o[j] = f2b(val);
    }
    u16* dst = PF + (size_t)pe*8;
    #pragma unroll
    for (int j=0;j<8;j++) dst[j] = o[j];
  }
}

// ---------------- Kernel 1: QKV projection — fused-m 12-wave blocks ----------------
// 1024 blocks x 768 thr. Block = 16 rows; wave (m = wv>>2, kq = wv&3) does 8 K-steps
// for matrix m; kq>0 partials reduced via 36 KB LDS by kq==0 wave of each m.
// x is HBM-fetched once; all m/K re-reads are intra-block (guaranteed L2 hits) —
// fixes round-2's FETCH_SIZE doubling (34->80 MB) from cross-block m re-reads.
__global__ __launch_bounds__(768, 8) void k_proj5(
    const void* __restrict__ x, const u16* __restrict__ WF,
    float* __restrict__ oq, float* __restrict__ ok_, float* __restrict__ ov,
    u16* __restrict__ qb16, u16* __restrict__ kb16, u16* __restrict__ vb16,
    const int* __restrict__ fl)
{
  __shared__ f32x4 red[9][4][64];   // 36 KB: 9 writer waves x 4 accs
  const int f32 = fl[0];
  const int rows0 = blockIdx.x*16;
  const int wv = threadIdx.x>>6;
  const int m  = wv>>2;          // 0:q 1:k 2:v
  const int kq = wv&3;           // K-quarter
  const int lane = threadIdx.x&63;
  const int quad = lane>>4, l16 = lane&15;
  const size_t rowA = (size_t)(rows0 + l16)*DM_;

  f32x4 acc[4];
  #pragma unroll
  for (int i=0;i<4;i++) acc[i] = (f32x4){0.f,0.f,0.f,0.f};

  const int ks0 = kq*8;
  #pragma unroll 2
  for (int kk=0;kk<8;kk++){
    int ks = ks0 + kk;
    int ko = ks*32 + quad*8;
    bf16x8 a = ld8bf(x, rowA + ko, f32);
    #pragma unroll
    for (int nt=0;nt<4;nt++){
      bf16x8 b = *(const bf16x8*)(WF + ((size_t)((m*32+ks)*4+nt)*64 + lane)*8);
      acc[nt] = __builtin_amdgcn_mfma_f32_16x16x32_bf16(a,b,acc[nt],0,0,0);
    }
  }

  if (kq>0){
    #pragma unroll
    for (int i=0;i<4;i++) red[m*3+(kq-1)][i][lane] = acc[i];
  }
  __syncthreads();
  if (kq==0){
    #pragma unroll
    for (int i=0;i<4;i++){
      f32x4 r0 = red[m*3+0][i][lane];
      f32x4 r1 = red[m*3+1][i][lane];
      f32x4 r2 = red[m*3+2][i][lane];
      acc[i][0]+=r0[0]+r1[0]+r2[0]; acc[i][1]+=r0[1]+r1[1]+r2[1];
      acc[i][2]+=r0[2]+r1[2]+r2[2]; acc[i][3]+=r0[3]+r1[3]+r2[3];
    }
    float* __restrict__ outp = (m==0)?oq:((m==1)?ok_:ov);
    u16* __restrict__ outb = (m==0)?qb16:((m==1)?kb16:vb16);
    #pragma unroll
    for (int nt=0;nt<4;nt++){
      #pragma unroll
      for (int i=0;i<4;i++){
        int row = rows0 + quad*4 + i;
        int col = nt*16 + l16;
        float val = acc[nt][i];
        if (m<2) val = (val>0.f)? (val+1.f) : expf(val);  // elu1
        outp[(size_t)row*DH_ + col] = val;
        outb[(size_t)row*DH_ + col] = f2b(val);
      }
    }
  }
}

// ---------------- Kernel 2: basis projections via MFMA — per-matrix split --------
__global__ __launch_bounds__(64) void k_prep3(
    const u16* __restrict__ qb16, const u16* __restrict__ kb16, const u16* __restrict__ vb16,
    const u16* __restrict__ PF,
    float* __restrict__ uLa, float* __restrict__ vRa, float* __restrict__ vrxa, float* __restrict__ vlxa)
{
  const int m = blockIdx.y;          // 0:uL=K@Mu 1:vR=V@Mv 2:vrx=Q@Mv 3:vlx=Q@Mlx
  const int rows0 = blockIdx.x*16;
  const int lane = threadIdx.x;
  const int quad = lane>>4, l16 = lane&15;

  const u16* __restrict__ src = (m==0)?kb16:((m==1)?vb16:qb16);
  const int mat = (m==0)?0:((m==3)?2:1);   // PF matrix index {Mu,Mv,Mlx}

  bf16x8 a[2];
  #pragma unroll
  for (int ks=0;ks<2;ks++){
    size_t off = (size_t)(rows0 + l16)*DH_ + ks*32 + quad*8;
    a[ks] = *(const bf16x8*)(src + off);
  }
  f32x4 acc[6];
  #pragma unroll
  for (int nt=0;nt<6;nt++) acc[nt] = (f32x4){0.f,0.f,0.f,0.f};

  #pragma unroll
  for (int ks=0;ks<2;ks++){
    #pragma unroll
    for (int nt=0;nt<6;nt++){
      bf16x8 b = *(const bf16x8*)(PF + ((size_t)((mat*2+ks)*6+nt)*64 + lane)*8);
      acc[nt] = __builtin_amdgcn_mfma_f32_16x16x32_bf16(a[ks], b, acc[nt],0,0,0);
    }
  }
  float* __restrict__ dst = (m==0)?uLa:(m==1)?vRa:(m==2)?vrxa:vlxa;
  #pragma unroll
  for (int nt=0;nt<6;nt++){
    int col = nt*16 + l16;
    if (col < 88){
      #pragma unroll
      for (int i=0;i<4;i++){
        int row = rows0 + quad*4 + i;
        dst[(size_t)row*88 + col] = acc[nt][i];
      }
    }
  }
}

// ---------------- Kernel 3: per-chunk state sums ----------------
__global__ __launch_bounds__(256) void k_chunksum(
    const float* __restrict__ gk, const float* __restrict__ gv,
    const float* __restrict__ uLa, const float* __restrict__ vRa,
    float* __restrict__ SL)
{
  const int bid = blockIdx.x;
  const int b = bid/NCH_, c = bid%NCH_;
  const size_t base64 = (size_t)(b*T_ + c*S_)*64;
  const size_t base88 = (size_t)(b*T_ + c*S_)*88;
  for (int p=0;p<4;p++){
    int e = threadIdx.x + p*256;
    if (e>=STATE_) break;
    float acc=0.f;
    if (e < 256){
      int n=e>>4;
      const float* A = gk + base64 + n*4 + ((e>>2)&3);
      const float* Bp = gv + base64 + n*4 + (e&3);
      for (int s=0;s<S_;s++) acc += A[s*64]*Bp[s*64];
    } else if (e < 832){
      int ia, ib; decodeWs(e, ia, ib);
      const float* A = uLa + base88 + ia;
      const float* Bp = vRa + base88 + ib;
      for (int s=0;s<S_;s++) acc += A[s*88]*Bp[s*88];
    } else {
      const float* A = gk + base64 + (e-832);
      for (int s=0;s<S_;s++) acc += A[s*64];
    }
    SL[(size_t)bid*STATE_ + e] = acc;
  }
}

// ---------------- Kernel 4: exclusive prefix over chunks ----------------
__global__ __launch_bounds__(256) void k_prefix(const float* __restrict__ SL, float* __restrict__ SP){
  const int b = blockIdx.x;
  for (int p=0;p<4;p++){
    int e = threadIdx.x + p*256;
    if (e>=STATE_) break;
    float run=0.f;
    for (int c=0;c<NCH_;c++){
      size_t idx = ((size_t)(b*NCH_+c))*STATE_ + e;
      SP[idx] = run; run += SL[idx];
    }
  }
}

// ---------------- Kernel 5: parallel intra-chunk ----------------
__global__ __launch_bounds__(256) void k_intra(
    const float* __restrict__ gq, const float* __restrict__ gk, const float* __restrict__ gv,
    const float* __restrict__ uLa, const float* __restrict__ vRa,
    const float* __restrict__ vrxa, const float* __restrict__ vlxa,
    const float* __restrict__ SP,
    const void* __restrict__ UL0, const void* __restrict__ UL1, const void* __restrict__ UL2, const void* __restrict__ UL3,
    const void* __restrict__ UR0, const void* __restrict__ UR1, const void* __restrict__ UR2, const void* __restrict__ UR3,
    u16* __restrict__ Yb, const int* __restrict__ fl)
{
  __shared__ float kS[S_*64];
  __shared__ float vS[S_*64];
  __shared__ float uvS[S_*176];
  __shared__ float st0[STATE_];
  __shared__ float ULs[464], URs[464];
  const int f32 = fl[0];
  const int tid = threadIdx.x;
  const int bid = blockIdx.x;
  const int b = bid/NCH_, c = bid%NCH_;
  const int row0 = b*T_ + c*S_;

  const size_t r64 = (size_t)row0*64;
  for (int i=tid;i<S_*64;i+=256){ kS[i]=gk[r64+i]; vS[i]=gv[r64+i]; }
  const size_t r88 = (size_t)row0*88;
  for (int i=tid;i<S_*88;i+=256){
    int s=i/88, f=i-s*88;
    uvS[s*176+f]    = uLa[r88+i];
    uvS[s*176+88+f] = vRa[r88+i];
  }
  for (int e=tid;e<STATE_;e+=256) st0[e] = SP[(size_t)bid*STATE_+e];
  for (int e=tid;e<464;e+=256){
    int l, idx;
    if (e<16){ l=0; idx=e; } else if (e<80){ l=1; idx=e-16; }
    else if (e<208){ l=2; idx=e-80; } else { l=3; idx=e-208; }
    const void* ul = (l==0)?UL0:(l==1)?UL1:(l==2)?UL2:UL3;
    const void* ur = (l==0)?UR0:(l==1)?UR1:(l==2)?UR2:UR3;
    ULs[e] = ldin(ul, idx, f32); URs[e] = ldin(ur, idx, f32);
  }
  __syncthreads();

  const int w = tid>>6, lane = tid&63, tl = lane>>3, g = lane&7;
  const int t = w*8 + tl;
  const int n1 = g>>1, ri1 = (g&1)*4;
  const int n2 = g>>2, ri2 = (g&3)*2;
  const size_t row = (size_t)(row0 + t);

  float qr[8];
  { const float* qp = gq + row*64 + g*8;
    *(f32x4*)&qr[0] = *(const f32x4*)qp; *(f32x4*)&qr[4] = *(const f32x4*)(qp+4); }
  float rxL0[4], lxL0[4], rxL1[8], lxL1[8], rxL2[8], lxL2[8], rxL3[8], lxL3[8];
  { const float* rp = vrxa + row*88; const float* lp = vlxa + row*88;
    *(f32x4*)&rxL0[0] = *(const f32x4*)(rp + 4*g);
    *(f32x4*)&lxL0[0] = *(const f32x4*)(lp + 4*g);
    *(f32x4*)&rxL1[0] = *(const f32x4*)(rp + 32 + n1*8); *(f32x4*)&rxL1[4] = *(const f32x4*)(rp + 36 + n1*8);
    *(f32x4*)&lxL1[0] = *(const f32x4*)(lp + 32 + n1*8); *(f32x4*)&lxL1[4] = *(const f32x4*)(lp + 36 + n1*8);
    *(f32x4*)&rxL2[0] = *(const f32x4*)(rp + 64 + n2*8); *(f32x4*)&rxL2[4] = *(const f32x4*)(rp + 68 + n2*8);
    *(f32x4*)&lxL2[0] = *(const f32x4*)(lp + 64 + n2*8); *(f32x4*)&lxL2[4] = *(const f32x4*)(lp + 68 + n2*8);
    *(f32x4*)&rxL3[0] = *(const f32x4*)(rp + 80); *(f32x4*)&rxL3[4] = *(const f32x4*)(rp + 84);
    *(f32x4*)&lxL3[0] = *(const f32x4*)(lp + 80); *(f32x4*)&lxL3[4] = *(const f32x4*)(lp + 84); }

  float yacc[8], den = 0.f;
  #pragma unroll
  for (int cc=0;cc<8;cc++){
    int n = 2*g + (cc>>2);
    const float* m = &st0[n*16 + (cc&3)*4];
    const float* qp = &qr[(cc>>2)*4];
    yacc[cc] = m[0]*qp[0]+m[1]*qp[1]+m[2]*qp[2]+m[3]*qp[3];
    den += st0[832 + g*8 + cc]*qr[cc];
  }
  float gtL0[4], gbL0[4], gtL1[4], gbL1[4], gtL2[2], gbL2[2], gtL3, gbL3;
  #pragma unroll
  for (int cc=0;cc<4;cc++){
    const float* m = &st0[256 + g*16 + cc*4];
    gtL0[cc] = m[0]*rxL0[0]+m[1]*rxL0[1]+m[2]*rxL0[2]+m[3]*rxL0[3];
    float s2 = 0.f;
    #pragma unroll
    for (int j=0;j<4;j++) s2 += st0[256 + g*16 + j*4 + cc]*lxL0[j];
    gbL0[cc] = s2;
  }
  #pragma unroll
  for (int cc=0;cc<4;cc++){
    int ri = ri1 + cc;
    float s1=0.f, s2=0.f;
    #pragma unroll
    for (int j=0;j<8;j++){
      s1 += st0[384 + n1*64 + ri*8 + j]*rxL1[j];
      s2 += st0[384 + n1*64 + j*8 + ri]*lxL1[j];
    }
    gtL1[cc]=s1; gbL1[cc]=s2;
  }
  #pragma unroll
  for (int cc=0;cc<2;cc++){
    int ri = ri2 + cc;
    float s1=0.f, s2=0.f;
    #pragma unroll
    for (int j=0;j<8;j++){
      s1 += st0[640 + n2*64 + ri*8 + j]*rxL2[j];
      s2 += st0[640 + n2*64 + j*8 + ri]*lxL2[j];
    }
    gtL2[cc]=s1; gbL2[cc]=s2;
  }
  { float s1=0.f, s2=0.f;
    #pragma unroll
    for (int j=0;j<8;j++){
      s1 += st0[768 + g*8 + j]*rxL3[j];
      s2 += st0[768 + j*8 + g]*lxL3[j];
    }
    gtL3=s1; gbL3=s2; }

  const int smax = w*8 + 8;
  for (int s=0; s<smax; s++){
    const float* ks_ = &kS[s*64 + g*8];
    const float* vs_ = &vS[s*64 + g*8];
    const float* uL_ = &uvS[s*176];
    const float* vR_ = &uvS[s*176 + 88];
    float dv0 = vs_[0]*qr[0]+vs_[1]*qr[1]+vs_[2]*qr[2]+vs_[3]*qr[3];
    float dv1 = vs_[4]*qr[4]+vs_[5]*qr[5]+vs_[6]*qr[6]+vs_[7]*qr[7];
    float dn = 0.f;
    #pragma unroll
    for (int cc=0;cc<8;cc++) dn += ks_[cc]*qr[cc];
    float d1L0=0.f,d2L0=0.f;
    #pragma unroll
    for (int j=0;j<4;j++){ d1L0 += vR_[4*g+j]*rxL0[j]; d2L0 += uL_[4*g+j]*lxL0[j]; }
    float d1L1=0.f,d2L1=0.f;
    #pragma unroll
    for (int j=0;j<8;j++){ d1L1 += vR_[32+n1*8+j]*rxL1[j]; d2L1 += uL_[32+n1*8+j]*lxL1[j]; }
    float d1L2=0.f,d2L2=0.f;
    #pragma unroll
    for (int j=0;j<8;j++){ d1L2 += vR_[64+n2*8+j]*rxL2[j]; d2L2 += uL_[64+n2*8+j]*lxL2[j]; }
    float d1L3=0.f,d2L3=0.f;
    #pragma unroll
    for (int j=0;j<8;j++){ d1L3 += vR_[80+j]*rxL3[j]; d2L3 += uL_[80+j]*lxL3[j]; }
    if (s<=t){
      den += dn;
      #pragma unroll
      for (int cc=0;cc<8;cc++) yacc[cc] += ks_[cc]*((cc<4)?dv0:dv1);
      #pragma unroll
      for (int cc=0;cc<4;cc++){
        gtL0[cc] += uL_[4*g+cc]*d1L0;          gbL0[cc] += vR_[4*g+cc]*d2L0;
        gtL1[cc] += uL_[32+n1*8+ri1+cc]*d1L1;  gbL1[cc] += vR_[32+n1*8+ri1+cc]*d2L1;
      }
      #pragma unroll
      for (int cc=0;cc<2;cc++){
        gtL2[cc] += uL_[64+n2*8+ri2+cc]*d1L2;  gbL2[cc] += vR_[64+n2*8+ri2+cc]*d2L2;
      }
      gtL3 += uL_[80+g]*d1L3;  gbL3 += vR_[80+g]*d2L3;
    }
  }
  __syncthreads();

  { float* gr = &uvS[t*176];
    #pragma unroll
    for (int cc=0;cc<4;cc++){
      gr[4*g+cc] = gtL0[cc];                 gr[88+4*g+cc] = gbL0[cc];
      gr[32+n1*8+ri1+cc] = gtL1[cc];         gr[88+32+n1*8+ri1+cc] = gbL1[cc];
    }
    #pragma unroll
    for (int cc=0;cc<2;cc++){
      gr[64+n2*8+ri2+cc] = gtL2[cc];         gr[88+64+n2*8+ri2+cc] = gbL2[cc];
    }
    gr[80+g] = gtL3;  gr[88+80+g] = gbL3;
  }
  __syncthreads();

  den += __shfl_xor(den,1); den += __shfl_xor(den,2); den += __shfl_xor(den,4);
  float inv = 1.f / fmaxf(den, 1e-6f);
  const float* gr = &uvS[t*176];
  float yout[8];
  #pragma unroll
  for (int cc=0;cc<8;cc++){
    int j = g*8 + cc;
    float y = yacc[cc];
    if (cc<4){
      #pragma unroll
      for (int rr=0;rr<4;rr++) y += ULs[cc*4+rr]*gr[g*4+rr];
    } else {
      #pragma unroll
      for (int rr=0;rr<4;rr++) y += URs[(cc-4)*4+rr]*gr[88+g*4+rr];
    }
    { int seg=j>>4, pos=j&15;
      if (pos<8){
        #pragma unroll
        for (int rr=0;rr<8;rr++) y += ULs[16+pos*8+rr]*gr[32+seg*8+rr];
      } else {
        #pragma unroll
        for (int rr=0;rr<8;rr++) y += URs[16+(pos-8)*8+rr]*gr[88+32+seg*8+rr];
      } }
    { int seg=j>>5, pos=j&31;
      if (pos<16){
        #pragma unroll
        for (int rr=0;rr<8;rr++) y += ULs[80+pos*8+rr]*gr[64+seg*8+rr];
      } else {
        #pragma unroll
        for (int rr=0;rr<8;rr++) y += URs[80+(pos-16)*8+rr]*gr[88+64+seg*8+rr];
      } }
    { int pos=j;
      if (pos<32){
        #pragma unroll
        for (int rr=0;rr<8;rr++) y += ULs[208+pos*8+rr]*gr[80+rr];
      } else {
        #pragma unroll
        for (int rr=0;rr<8;rr++) y += URs[208+(pos-32)*8+rr]*gr[88+80+rr];
      } }
    yout[cc] = y*inv;
  }
  u16* yp = Yb + row*64 + g*8;
  ushort4 o1, o2;
  o1.x=f2b(yout[0]); o1.y=f2b(yout[1]); o1.z=f2b(yout[2]); o1.w=f2b(yout[3]);
  o2.x=f2b(yout[4]); o2.y=f2b(yout[5]); o2.z=f2b(yout[6]); o2.w=f2b(yout[7]);
  *(ushort4*)yp = o1;
  *(ushort4*)(yp+4) = o2;
}

// ---------------- Kernel 6: output projection — 8-way col split ----------------
__global__ __launch_bounds__(64,4) void k_outproj3(
    const u16* __restrict__ Yb, const u16* __restrict__ WoF, void* __restrict__ outv,
    const int* __restrict__ fl)
{
  const int f32 = fl[0];
  const int rows0 = blockIdx.x*32;
  const int nt0 = blockIdx.y*8;
  const int lane = threadIdx.x;
  const int quad = lane>>4, l16 = lane&15;

  f32x4 acc[16];
  #pragma unroll
  for (int i=0;i<16;i++) acc[i] = (f32x4){0.f,0.f,0.f,0.f};

  #pragma unroll
  for (int ks=0;ks<2;ks++){
    int ko = ks*32 + quad*8;
    bf16x8 a0 = *(const bf16x8*)(Yb + (size_t)(rows0 + l16)*DH_ + ko);
    bf16x8 a1 = *(const bf16x8*)(Yb + (size_t)(rows0 + 16 + l16)*DH_ + ko);
    #pragma unroll
    for (int nt=0;nt<8;nt++){
      bf16x8 b = *(const bf16x8*)(WoF + ((size_t)(ks*64 + nt0 + nt)*64 + lane)*8);
      acc[nt]   = __builtin_amdgcn_mfma_f32_16x16x32_bf16(a0,b,acc[nt],0,0,0);
      acc[8+nt] = __builtin_amdgcn_mfma_f32_16x16x32_bf16(a1,b,acc[8+nt],0,0,0);
    }
  }
  #pragma unroll
  for (int sp=0;sp<2;sp++){
    #pragma unroll
    for (int nt=0;nt<8;nt++){
      #pragma unroll
      for (int i=0;i<4;i++){
        int row = rows0 + sp*16 + quad*4 + i;
        int col = (nt0+nt)*16 + l16;
        size_t idx = (size_t)row*DM_ + col;
        float v = acc[sp*8+nt][i];
        if (f32) ((float*)outv)[idx] = v;
        else ((u16*)outv)[idx] = f2b(v);
      }
    }
  }
}

extern "C" void kernel_launch(void* const* d_in, const int* in_sizes, int n_in,
                              void* d_out, int out_size, void* d_ws, size_t ws_size,
                              hipStream_t stream) {
  const void* x  = d_in[0];
  const void* Wq = d_in[1];
  const void* Wk = d_in[2];
  const void* Wv = d_in[3];
  const void* Wo = d_in[4];
  const void* UL[4] = {d_in[5],d_in[6],d_in[7],d_in[8]};
  const void* VR[4] = {d_in[9],d_in[10],d_in[11],d_in[12]};
  const void* UR[4] = {d_in[13],d_in[14],d_in[15],d_in[16]};
  const void* VL[4] = {d_in[17],d_in[18],d_in[19],d_in[20]};

  int* flag = (int*)d_ws;
  float* ws = (float*)d_ws + 16;
  float* q    = ws;
  float* kf   = q    + (size_t)BT_*64;
  float* vf   = kf   + (size_t)BT_*64;
  float* uLa  = vf   + (size_t)BT_*64;
  float* vRa  = uLa  + (size_t)BT_*88;
  float* vrxa = vRa  + (size_t)BT_*88;
  float* vlxa = vrxa + (size_t)BT_*88;
  float* SL   = vlxa + (size_t)BT_*88;
  float* SP   = SL   + (size_t)B_*NCH_*STATE_;
  u16*   Yb   = (u16*)(SP + (size_t)B_*NCH_*STATE_);
  u16*   WF   = Yb  + (size_t)BT_*64;
  u16*   WoF  = WF  + (size_t)196608;
  u16*   PF   = WoF + (size_t)65536;
  u16*   qb16 = PF  + (size_t)18432;
  u16*   kb16 = qb16 + (size_t)BT_*64;
  u16*   vb16 = kb16 + (size_t)BT_*64;

  k_detect<<<1, 64, 0, stream>>>((const u16*)x, flag);
  k_wfrag<<<137, 256, 0, stream>>>(Wq, Wk, Wv, Wo,
      UL[0],UL[1],UL[2],UL[3], VR[0],VR[1],VR[2],VR[3], VL[0],VL[1],VL[2],VL[3],
      WF, WoF, PF, flag);
  k_proj5<<<BT_/16, 768, 0, stream>>>(x, WF, q, kf, vf, qb16, kb16, vb16, flag);
  k_prep3<<<dim3(BT_/16, 4), 64, 0, stream>>>(qb16, kb16, vb16, PF, uLa, vRa, vrxa, vlxa);
  k_chunksum<<<B_*NCH_, 256, 0, stream>>>(kf, vf, uLa, vRa, SL);
  k_prefix<<<B_, 256, 0, stream>>>(SL, SP);
  k_intra<<<B_*NCH_, 256, 0, stream>>>(q, kf, vf, uLa, vRa, vrxa, vlxa, SP,
      UL[0],UL[1],UL[2],UL[3], UR[0],UR[1],UR[2],UR[3], Yb, flag);
  k_outproj3<<<dim3(512, 8), 64, 0, stream>>>(Yb, WoF, d_out, flag);
}

// Round 4
// 277.763 us; speedup vs baseline: 1.0054x; 1.0015x over previous
//
#include <hip/hip_runtime.h>
#include <hip/hip_bf16.h>

typedef unsigned short u16;
typedef __attribute__((ext_vector_type(8))) short bf16x8;
typedef __attribute__((ext_vector_type(4))) float f32x4;

#define B_ 8
#define T_ 2048
#define BT_ (B_*T_)
#define DM_ 1024
#define DH_ 64
#define NCH_ 64            // chunks per batch
#define S_ (T_/NCH_)       // 32 steps per chunk
#define STATE_ 896         // leaf 256 + Ws 576 + z 64

__device__ __forceinline__ float b2f(u16 u){ unsigned v=((unsigned)u)<<16; float f; __builtin_memcpy(&f,&v,4); return f; }
__device__ __forceinline__ u16 f2b(float f){ __hip_bfloat16 h=__float2bfloat16(f); u16 u; __builtin_memcpy(&u,&h,2); return u; }

__device__ __forceinline__ float ldin(const void* p, size_t i, int f32){
  return f32 ? ((const float*)p)[i] : b2f(((const u16*)p)[i]);
}
// load 8 consecutive elements as bf16x8 (converting from fp32 if needed)
__device__ __forceinline__ bf16x8 ld8bf(const void* p, size_t i, int f32){
  if (f32){
    f32x4 v0 = *(const f32x4*)((const float*)p + i);
    f32x4 v1 = *(const f32x4*)((const float*)p + i + 4);
    bf16x8 r;
    #pragma unroll
    for (int j=0;j<4;j++){ r[j] = (short)f2b(v0[j]); r[4+j] = (short)f2b(v1[j]); }
    return r;
  }
  return *(const bf16x8*)((const u16*)p + i);
}

// async global->LDS, 16B per lane
__device__ __forceinline__ void gl_lds16(const void* g, void* l){
  __builtin_amdgcn_global_load_lds((const __attribute__((address_space(1))) unsigned int*)g,
                                   (__attribute__((address_space(3))) unsigned int*)l, 16, 0, 0);
}

// state layout: leaf [0,256): n*16+i*4+j ; Ws: L0@256, L1@384, L2@640, L3@768 ; z@832
__device__ __forceinline__ void decodeWs(int e, int& ia, int& ib){
  if (e<384){ int o=e-256, n=o>>4; ia=n*4+((o>>2)&3); ib=n*4+(o&3); }
  else if (e<640){ int o=e-384, n=o>>6; ia=32+n*8+((o>>3)&7); ib=32+n*8+(o&7); }
  else if (e<768){ int o=e-640, n=o>>6; ia=64+n*8+((o>>3)&7); ib=64+n*8+(o&7); }
  else { int o=e-768; ia=80+((o>>3)&7); ib=80+(o&7); }
}
__device__ __forceinline__ void decode88(int f, int& l, int& n, int& ri){
  if (f<32){ l=0; n=f>>2; ri=f&3; }
  else if (f<64){ l=1; n=(f-32)>>3; ri=f&7; }
  else if (f<80){ l=2; n=(f-64)>>3; ri=f&7; }
  else { l=3; n=0; ri=f&7; }
}

// ---------------- Kernel 0: dtype detection ----------------
__global__ __launch_bounds__(64) void k_detect(const u16* __restrict__ x, int* __restrict__ flag){
  int tid = threadIdx.x;
  int sane = 0;
  for (int i = tid; i < 4096; i += 64){
    u16 u = x[i];
    int e = (u >> 7) & 0xFF;
    if ((u & 0x7FFF) == 0 || (e >= 100 && e <= 140)) sane++;
  }
  #pragma unroll
  for (int o = 32; o > 0; o >>= 1) sane += __shfl_down(sane, o);
  if (tid == 0) flag[0] = (sane < 3600) ? 1 : 0;
}

// ---------------- Kernel 0c: weight/basis -> MFMA B-fragment layout (bf16) ------
__global__ __launch_bounds__(256) void k_wfrag(
    const void* __restrict__ Wq, const void* __restrict__ Wk, const void* __restrict__ Wv,
    const void* __restrict__ Wo,
    const void* __restrict__ UL0, const void* __restrict__ UL1, const void* __restrict__ UL2, const void* __restrict__ UL3,
    const void* __restrict__ VR0, const void* __restrict__ VR1, const void* __restrict__ VR2, const void* __restrict__ VR3,
    const void* __restrict__ VL0, const void* __restrict__ VL1, const void* __restrict__ VL2, const void* __restrict__ VL3,
    u16* __restrict__ WF, u16* __restrict__ WoF, u16* __restrict__ PF,
    const int* __restrict__ fl)
{
  const int f32 = fl[0];
  int e = blockIdx.x*256 + threadIdx.x;
  if (e < 24576){
    int m = e >> 13;
    int rem = e & 8191;
    int ks = rem >> 8;
    int nt = (rem >> 6) & 3;
    int lane = rem & 63;
    const void* W = (m==0)?Wq:((m==1)?Wk:Wv);
    int kr = ks*32 + (lane>>4)*8;
    int col = nt*16 + (lane&15);
    u16 o[8];
    #pragma unroll
    for (int j=0;j<8;j++) o[j] = f2b(ldin(W, (size_t)(kr+j)*DH_ + col, f32));
    u16* dst = WF + (size_t)e*8;
    #pragma unroll
    for (int j=0;j<8;j++) dst[j] = o[j];
  } else if (e < 32768){
    int eo = e - 24576;
    int ks = eo >> 12;
    int nt = (eo >> 6) & 63;
    int lane = eo & 63;
    int kr = ks*32 + (lane>>4)*8;
    int col = nt*16 + (lane&15);
    u16 o[8];
    #pragma unroll
    for (int j=0;j<8;j++) o[j] = f2b(ldin(Wo, (size_t)(kr+j)*DM_ + col, f32));
    u16* dst = WoF + (size_t)eo*8;
    #pragma unroll
    for (int j=0;j<8;j++) dst[j] = o[j];
  } else if (e < 35072){
    int pe = e - 32768;         // 0..2303
    int lane = pe & 63;
    int nt = (pe >> 6) % 6;
    int mk = pe / 384;          // mat*2+ks
    int ks = mk & 1, mat = mk >> 1;
    int col = nt*16 + (lane&15);
    int dbase = ks*32 + (lane>>4)*8;
    const int BSl[4]={4,8,16,32}; const int Rl[4]={4,8,8,8};
    u16 o[8];
    #pragma unroll
    for (int j=0;j<8;j++){
      float val = 0.f;
      if (col < 88){
        int l,n,ri; decode88(col,l,n,ri);
        int bs=BSl[l], r=Rl[l];
        int lo = n*2*bs + ((mat==1)?bs:0);
        int d = dbase + j;
        if (d >= lo && d < lo+bs){
          const void* Up;
          if (mat==0)      Up = (l==0)?UL0:(l==1)?UL1:(l==2)?UL2:UL3;
          else if (mat==1) Up = (l==0)?VR0:(l==1)?VR1:(l==2)?VR2:VR3;
          else             Up = (l==0)?VL0:(l==1)?VL1:(l==2)?VL2:VL3;
          val = ldin(Up, (size_t)(d-lo)*r + ri, f32);
        }
      }
      o[j] = f2b(val);
    }
    u16* dst = PF + (size_t)pe*8;
    #pragma unroll
    for (int j=0;j<8;j++) dst[j] = o[j];
  }
}

// ---------------- Kernel 1: QKV projection — LDS-staged x, register-MLP ----------
// 1024 blocks x 768 thr (12 waves: m=wv>>2, kq=wv&3). Block = 16 rows of x
// (32 KB contiguous) staged ONCE to LDS via global_load_lds (async, no VGPRs,
// full MLP) with XOR-swizzled source (a ^= ((a>>11)&7)<<4) so stride-2KB
// ds_read_b128 a-frag reads are conflict-free. launch_bounds(768,6): VGPR<=85
// (round-3's (768,8) forced VGPR=40 -> compiler serialized every load with
// vmcnt(0) -> ~7000cy/iter). Reduction buffer aliases the stage buffer.
__global__ __launch_bounds__(768, 6) void k_proj6(
    const void* __restrict__ x, const u16* __restrict__ WF,
    float* __restrict__ oq, float* __restrict__ ok_, float* __restrict__ ov,
    u16* __restrict__ qb16, u16* __restrict__ kb16, u16* __restrict__ vb16,
    const int* __restrict__ fl)
{
  __shared__ __align__(16) char shmem[36864];   // 32 KB x-tile | 36 KB reduction (aliased)
  u16* xS = (u16*)shmem;
  f32x4 (*red)[4][64] = (f32x4 (*)[4][64])shmem;

  const int f32 = fl[0];
  const int tid = threadIdx.x;
  const int rows0 = blockIdx.x*16;
  const int wv = tid>>6;
  const int m  = wv>>2;          // 0:q 1:k 2:v
  const int kq = wv&3;           // K-quarter (8 K-steps each)
  const int lane = tid&63;
  const int quad = lane>>4, l16 = lane&15;

  if (!f32){
    // stage 16 rows x 2048 B = 2048 granules of 16 B, source pre-swizzled
    const char* gbase = (const char*)x + (size_t)rows0*2048;
    #pragma unroll
    for (int r=0;r<3;r++){
      int i = tid + r*768;
      if (i < 2048){
        int lofs = i*16;
        int gofs = lofs ^ (((lofs>>11)&7)<<4);
        gl_lds16(gbase + gofs, (char*)shmem + lofs);
      }
    }
    asm volatile("s_waitcnt vmcnt(0)" ::: "memory");
  }
  __syncthreads();

  f32x4 acc[4];
  #pragma unroll
  for (int i=0;i<4;i++) acc[i] = (f32x4){0.f,0.f,0.f,0.f};

  const int ks0 = kq*8;
  if (!f32){
    #pragma unroll
    for (int kk=0;kk<8;kk++){
      int ks = ks0 + kk;
      int byte = (l16<<11) + (ks<<6) + (quad<<4);
      byte ^= (l16&7)<<4;
      bf16x8 a = *(const bf16x8*)(xS + (byte>>1));
      const u16* wp = WF + ((size_t)((m*32+ks)*4)*64 + lane)*8;
      bf16x8 b0 = *(const bf16x8*)(wp);
      bf16x8 b1 = *(const bf16x8*)(wp + 512);
      bf16x8 b2 = *(const bf16x8*)(wp + 1024);
      bf16x8 b3 = *(const bf16x8*)(wp + 1536);
      acc[0] = __builtin_amdgcn_mfma_f32_16x16x32_bf16(a,b0,acc[0],0,0,0);
      acc[1] = __builtin_amdgcn_mfma_f32_16x16x32_bf16(a,b1,acc[1],0,0,0);
      acc[2] = __builtin_amdgcn_mfma_f32_16x16x32_bf16(a,b2,acc[2],0,0,0);
      acc[3] = __builtin_amdgcn_mfma_f32_16x16x32_bf16(a,b3,acc[3],0,0,0);
    }
  } else {
    const size_t rowA = (size_t)(rows0 + l16)*DM_;
    #pragma unroll 2
    for (int kk=0;kk<8;kk++){
      int ks = ks0 + kk;
      bf16x8 a = ld8bf(x, rowA + ks*32 + quad*8, 1);
      const u16* wp = WF + ((size_t)((m*32+ks)*4)*64 + lane)*8;
      bf16x8 b0 = *(const bf16x8*)(wp);
      bf16x8 b1 = *(const bf16x8*)(wp + 512);
      bf16x8 b2 = *(const bf16x8*)(wp + 1024);
      bf16x8 b3 = *(const bf16x8*)(wp + 1536);
      acc[0] = __builtin_amdgcn_mfma_f32_16x16x32_bf16(a,b0,acc[0],0,0,0);
      acc[1] = __builtin_amdgcn_mfma_f32_16x16x32_bf16(a,b1,acc[1],0,0,0);
      acc[2] = __builtin_amdgcn_mfma_f32_16x16x32_bf16(a,b2,acc[2],0,0,0);
      acc[3] = __builtin_amdgcn_mfma_f32_16x16x32_bf16(a,b3,acc[3],0,0,0);
    }
  }
  __syncthreads();   // all xS reads done before red overwrites the buffer

  if (kq>0){
    #pragma unroll
    for (int i=0;i<4;i++) red[m*3+(kq-1)][i][lane] = acc[i];
  }
  __syncthreads();
  if (kq==0){
    #pragma unroll
    for (int i=0;i<4;i++){
      f32x4 r0 = red[m*3+0][i][lane];
      f32x4 r1 = red[m*3+1][i][lane];
      f32x4 r2 = red[m*3+2][i][lane];
      acc[i][0]+=r0[0]+r1[0]+r2[0]; acc[i][1]+=r0[1]+r1[1]+r2[1];
      acc[i][2]+=r0[2]+r1[2]+r2[2]; acc[i][3]+=r0[3]+r1[3]+r2[3];
    }
    float* __restrict__ outp = (m==0)?oq:((m==1)?ok_:ov);
    u16* __restrict__ outb = (m==0)?qb16:((m==1)?kb16:vb16);
    #pragma unroll
    for (int nt=0;nt<4;nt++){
      #pragma unroll
      for (int i=0;i<4;i++){
        int row = rows0 + quad*4 + i;
        int col = nt*16 + l16;
        float val = acc[nt][i];
        if (m<2) val = (val>0.f)? (val+1.f) : expf(val);  // elu1
        outp[(size_t)row*DH_ + col] = val;
        outb[(size_t)row*DH_ + col] = f2b(val);
      }
    }
  }
}

// ---------------- Kernel 2: basis projections via MFMA — per-matrix split --------
__global__ __launch_bounds__(64) void k_prep3(
    const u16* __restrict__ qb16, const u16* __restrict__ kb16, const u16* __restrict__ vb16,
    const u16* __restrict__ PF,
    float* __restrict__ uLa, float* __restrict__ vRa, float* __restrict__ vrxa, float* __restrict__ vlxa)
{
  const int m = blockIdx.y;          // 0:uL=K@Mu 1:vR=V@Mv 2:vrx=Q@Mv 3:vlx=Q@Mlx
  const int rows0 = blockIdx.x*16;
  const int lane = threadIdx.x;
  const int quad = lane>>4, l16 = lane&15;

  const u16* __restrict__ src = (m==0)?kb16:((m==1)?vb16:qb16);
  const int mat = (m==0)?0:((m==3)?2:1);   // PF matrix index {Mu,Mv,Mlx}

  bf16x8 a[2];
  #pragma unroll
  for (int ks=0;ks<2;ks++){
    size_t off = (size_t)(rows0 + l16)*DH_ + ks*32 + quad*8;
    a[ks] = *(const bf16x8*)(src + off);
  }
  f32x4 acc[6];
  #pragma unroll
  for (int nt=0;nt<6;nt++) acc[nt] = (f32x4){0.f,0.f,0.f,0.f};

  #pragma unroll
  for (int ks=0;ks<2;ks++){
    #pragma unroll
    for (int nt=0;nt<6;nt++){
      bf16x8 b = *(const bf16x8*)(PF + ((size_t)((mat*2+ks)*6+nt)*64 + lane)*8);
      acc[nt] = __builtin_amdgcn_mfma_f32_16x16x32_bf16(a[ks], b, acc[nt],0,0,0);
    }
  }
  float* __restrict__ dst = (m==0)?uLa:(m==1)?vRa:(m==2)?vrxa:vlxa;
  #pragma unroll
  for (int nt=0;nt<6;nt++){
    int col = nt*16 + l16;
    if (col < 88){
      #pragma unroll
      for (int i=0;i<4;i++){
        int row = rows0 + quad*4 + i;
        dst[(size_t)row*88 + col] = acc[nt][i];
      }
    }
  }
}

// ---------------- Kernel 3: per-chunk state sums ----------------
__global__ __launch_bounds__(256) void k_chunksum(
    const float* __restrict__ gk, const float* __restrict__ gv,
    const float* __restrict__ uLa, const float* __restrict__ vRa,
    float* __restrict__ SL)
{
  const int bid = blockIdx.x;
  const int b = bid/NCH_, c = bid%NCH_;
  const size_t base64 = (size_t)(b*T_ + c*S_)*64;
  const size_t base88 = (size_t)(b*T_ + c*S_)*88;
  for (int p=0;p<4;p++){
    int e = threadIdx.x + p*256;
    if (e>=STATE_) break;
    float acc=0.f;
    if (e < 256){
      int n=e>>4;
      const float* A = gk + base64 + n*4 + ((e>>2)&3);
      const float* Bp = gv + base64 + n*4 + (e&3);
      for (int s=0;s<S_;s++) acc += A[s*64]*Bp[s*64];
    } else if (e < 832){
      int ia, ib; decodeWs(e, ia, ib);
      const float* A = uLa + base88 + ia;
      const float* Bp = vRa + base88 + ib;
      for (int s=0;s<S_;s++) acc += A[s*88]*Bp[s*88];
    } else {
      const float* A = gk + base64 + (e-832);
      for (int s=0;s<S_;s++) acc += A[s*64];
    }
    SL[(size_t)bid*STATE_ + e] = acc;
  }
}

// ---------------- Kernel 4: exclusive prefix over chunks ----------------
__global__ __launch_bounds__(256) void k_prefix(const float* __restrict__ SL, float* __restrict__ SP){
  const int b = blockIdx.x;
  for (int p=0;p<4;p++){
    int e = threadIdx.x + p*256;
    if (e>=STATE_) break;
    float run=0.f;
    for (int c=0;c<NCH_;c++){
      size_t idx = ((size_t)(b*NCH_+c))*STATE_ + e;
      SP[idx] = run; run += SL[idx];
    }
  }
}

// ---------------- Kernel 5: parallel intra-chunk ----------------
__global__ __launch_bounds__(256) void k_intra(
    const float* __restrict__ gq, const float* __restrict__ gk, const float* __restrict__ gv,
    const float* __restrict__ uLa, const float* __restrict__ vRa,
    const float* __restrict__ vrxa, const float* __restrict__ vlxa,
    const float* __restrict__ SP,
    const void* __restrict__ UL0, const void* __restrict__ UL1, const void* __restrict__ UL2, const void* __restrict__ UL3,
    const void* __restrict__ UR0, const void* __restrict__ UR1, const void* __restrict__ UR2, const void* __restrict__ UR3,
    u16* __restrict__ Yb, const int* __restrict__ fl)
{
  __shared__ float kS[S_*64];
  __shared__ float vS[S_*64];
  __shared__ float uvS[S_*176];
  __shared__ float st0[STATE_];
  __shared__ float ULs[464], URs[464];
  const int f32 = fl[0];
  const int tid = threadIdx.x;
  const int bid = blockIdx.x;
  const int b = bid/NCH_, c = bid%NCH_;
  const int row0 = b*T_ + c*S_;

  const size_t r64 = (size_t)row0*64;
  for (int i=tid;i<S_*64;i+=256){ kS[i]=gk[r64+i]; vS[i]=gv[r64+i]; }
  const size_t r88 = (size_t)row0*88;
  for (int i=tid;i<S_*88;i+=256){
    int s=i/88, f=i-s*88;
    uvS[s*176+f]    = uLa[r88+i];
    uvS[s*176+88+f] = vRa[r88+i];
  }
  for (int e=tid;e<STATE_;e+=256) st0[e] = SP[(size_t)bid*STATE_+e];
  for (int e=tid;e<464;e+=256){
    int l, idx;
    if (e<16){ l=0; idx=e; } else if (e<80){ l=1; idx=e-16; }
    else if (e<208){ l=2; idx=e-80; } else { l=3; idx=e-208; }
    const void* ul = (l==0)?UL0:(l==1)?UL1:(l==2)?UL2:UL3;
    const void* ur = (l==0)?UR0:(l==1)?UR1:(l==2)?UR2:UR3;
    ULs[e] = ldin(ul, idx, f32); URs[e] = ldin(ur, idx, f32);
  }
  __syncthreads();

  const int w = tid>>6, lane = tid&63, tl = lane>>3, g = lane&7;
  const int t = w*8 + tl;
  const int n1 = g>>1, ri1 = (g&1)*4;
  const int n2 = g>>2, ri2 = (g&3)*2;
  const size_t row = (size_t)(row0 + t);

  float qr[8];
  { const float* qp = gq + row*64 + g*8;
    *(f32x4*)&qr[0] = *(const f32x4*)qp; *(f32x4*)&qr[4] = *(const f32x4*)(qp+4); }
  float rxL0[4], lxL0[4], rxL1[8], lxL1[8], rxL2[8], lxL2[8], rxL3[8], lxL3[8];
  { const float* rp = vrxa + row*88; const float* lp = vlxa + row*88;
    *(f32x4*)&rxL0[0] = *(const f32x4*)(rp + 4*g);
    *(f32x4*)&lxL0[0] = *(const f32x4*)(lp + 4*g);
    *(f32x4*)&rxL1[0] = *(const f32x4*)(rp + 32 + n1*8); *(f32x4*)&rxL1[4] = *(const f32x4*)(rp + 36 + n1*8);
    *(f32x4*)&lxL1[0] = *(const f32x4*)(lp + 32 + n1*8); *(f32x4*)&lxL1[4] = *(const f32x4*)(lp + 36 + n1*8);
    *(f32x4*)&rxL2[0] = *(const f32x4*)(rp + 64 + n2*8); *(f32x4*)&rxL2[4] = *(const f32x4*)(rp + 68 + n2*8);
    *(f32x4*)&lxL2[0] = *(const f32x4*)(lp + 64 + n2*8); *(f32x4*)&lxL2[4] = *(const f32x4*)(lp + 68 + n2*8);
    *(f32x4*)&rxL3[0] = *(const f32x4*)(rp + 80); *(f32x4*)&rxL3[4] = *(const f32x4*)(rp + 84);
    *(f32x4*)&lxL3[0] = *(const f32x4*)(lp + 80); *(f32x4*)&lxL3[4] = *(const f32x4*)(lp + 84); }

  float yacc[8], den = 0.f;
  #pragma unroll
  for (int cc=0;cc<8;cc++){
    int n = 2*g + (cc>>2);
    const float* m = &st0[n*16 + (cc&3)*4];
    const float* qp = &qr[(cc>>2)*4];
    yacc[cc] = m[0]*qp[0]+m[1]*qp[1]+m[2]*qp[2]+m[3]*qp[3];
    den += st0[832 + g*8 + cc]*qr[cc];
  }
  float gtL0[4], gbL0[4], gtL1[4], gbL1[4], gtL2[2], gbL2[2], gtL3, gbL3;
  #pragma unroll
  for (int cc=0;cc<4;cc++){
    const float* m = &st0[256 + g*16 + cc*4];
    gtL0[cc] = m[0]*rxL0[0]+m[1]*rxL0[1]+m[2]*rxL0[2]+m[3]*rxL0[3];
    float s2 = 0.f;
    #pragma unroll
    for (int j=0;j<4;j++) s2 += st0[256 + g*16 + j*4 + cc]*lxL0[j];
    gbL0[cc] = s2;
  }
  #pragma unroll
  for (int cc=0;cc<4;cc++){
    int ri = ri1 + cc;
    float s1=0.f, s2=0.f;
    #pragma unroll
    for (int j=0;j<8;j++){
      s1 += st0[384 + n1*64 + ri*8 + j]*rxL1[j];
      s2 += st0[384 + n1*64 + j*8 + ri]*lxL1[j];
    }
    gtL1[cc]=s1; gbL1[cc]=s2;
  }
  #pragma unroll
  for (int cc=0;cc<2;cc++){
    int ri = ri2 + cc;
    float s1=0.f, s2=0.f;
    #pragma unroll
    for (int j=0;j<8;j++){
      s1 += st0[640 + n2*64 + ri*8 + j]*rxL2[j];
      s2 += st0[640 + n2*64 + j*8 + ri]*lxL2[j];
    }
    gtL2[cc]=s1; gbL2[cc]=s2;
  }
  { float s1=0.f, s2=0.f;
    #pragma unroll
    for (int j=0;j<8;j++){
      s1 += st0[768 + g*8 + j]*rxL3[j];
      s2 += st0[768 + j*8 + g]*lxL3[j];
    }
    gtL3=s1; gbL3=s2; }

  const int smax = w*8 + 8;
  for (int s=0; s<smax; s++){
    const float* ks_ = &kS[s*64 + g*8];
    const float* vs_ = &vS[s*64 + g*8];
    const float* uL_ = &uvS[s*176];
    const float* vR_ = &uvS[s*176 + 88];
    float dv0 = vs_[0]*qr[0]+vs_[1]*qr[1]+vs_[2]*qr[2]+vs_[3]*qr[3];
    float dv1 = vs_[4]*qr[4]+vs_[5]*qr[5]+vs_[6]*qr[6]+vs_[7]*qr[7];
    float dn = 0.f;
    #pragma unroll
    for (int cc=0;cc<8;cc++) dn += ks_[cc]*qr[cc];
    float d1L0=0.f,d2L0=0.f;
    #pragma unroll
    for (int j=0;j<4;j++){ d1L0 += vR_[4*g+j]*rxL0[j]; d2L0 += uL_[4*g+j]*lxL0[j]; }
    float d1L1=0.f,d2L1=0.f;
    #pragma unroll
    for (int j=0;j<8;j++){ d1L1 += vR_[32+n1*8+j]*rxL1[j]; d2L1 += uL_[32+n1*8+j]*lxL1[j]; }
    float d1L2=0.f,d2L2=0.f;
    #pragma unroll
    for (int j=0;j<8;j++){ d1L2 += vR_[64+n2*8+j]*rxL2[j]; d2L2 += uL_[64+n2*8+j]*lxL2[j]; }
    float d1L3=0.f,d2L3=0.f;
    #pragma unroll
    for (int j=0;j<8;j++){ d1L3 += vR_[80+j]*rxL3[j]; d2L3 += uL_[80+j]*lxL3[j]; }
    if (s<=t){
      den += dn;
      #pragma unroll
      for (int cc=0;cc<8;cc++) yacc[cc] += ks_[cc]*((cc<4)?dv0:dv1);
      #pragma unroll
      for (int cc=0;cc<4;cc++){
        gtL0[cc] += uL_[4*g+cc]*d1L0;          gbL0[cc] += vR_[4*g+cc]*d2L0;
        gtL1[cc] += uL_[32+n1*8+ri1+cc]*d1L1;  gbL1[cc] += vR_[32+n1*8+ri1+cc]*d2L1;
      }
      #pragma unroll
      for (int cc=0;cc<2;cc++){
        gtL2[cc] += uL_[64+n2*8+ri2+cc]*d1L2;  gbL2[cc] += vR_[64+n2*8+ri2+cc]*d2L2;
      }
      gtL3 += uL_[80+g]*d1L3;  gbL3 += vR_[80+g]*d2L3;
    }
  }
  __syncthreads();

  { float* gr = &uvS[t*176];
    #pragma unroll
    for (int cc=0;cc<4;cc++){
      gr[4*g+cc] = gtL0[cc];                 gr[88+4*g+cc] = gbL0[cc];
      gr[32+n1*8+ri1+cc] = gtL1[cc];         gr[88+32+n1*8+ri1+cc] = gbL1[cc];
    }
    #pragma unroll
    for (int cc=0;cc<2;cc++){
      gr[64+n2*8+ri2+cc] = gtL2[cc];         gr[88+64+n2*8+ri2+cc] = gbL2[cc];
    }
    gr[80+g] = gtL3;  gr[88+80+g] = gbL3;
  }
  __syncthreads();

  den += __shfl_xor(den,1); den += __shfl_xor(den,2); den += __shfl_xor(den,4);
  float inv = 1.f / fmaxf(den, 1e-6f);
  const float* gr = &uvS[t*176];
  float yout[8];
  #pragma unroll
  for (int cc=0;cc<8;cc++){
    int j = g*8 + cc;
    float y = yacc[cc];
    if (cc<4){
      #pragma unroll
      for (int rr=0;rr<4;rr++) y += ULs[cc*4+rr]*gr[g*4+rr];
    } else {
      #pragma unroll
      for (int rr=0;rr<4;rr++) y += URs[(cc-4)*4+rr]*gr[88+g*4+rr];
    }
    { int seg=j>>4, pos=j&15;
      if (pos<8){
        #pragma unroll
        for (int rr=0;rr<8;rr++) y += ULs[16+pos*8+rr]*gr[32+seg*8+rr];
      } else {
        #pragma unroll
        for (int rr=0;rr<8;rr++) y += URs[16+(pos-8)*8+rr]*gr[88+32+seg*8+rr];
      } }
    { int seg=j>>5, pos=j&31;
      if (pos<16){
        #pragma unroll
        for (int rr=0;rr<8;rr++) y += ULs[80+pos*8+rr]*gr[64+seg*8+rr];
      } else {
        #pragma unroll
        for (int rr=0;rr<8;rr++) y += URs[80+(pos-16)*8+rr]*gr[88+64+seg*8+rr];
      } }
    { int pos=j;
      if (pos<32){
        #pragma unroll
        for (int rr=0;rr<8;rr++) y += ULs[208+pos*8+rr]*gr[80+rr];
      } else {
        #pragma unroll
        for (int rr=0;rr<8;rr++) y += URs[208+(pos-32)*8+rr]*gr[88+80+rr];
      } }
    yout[cc] = y*inv;
  }
  u16* yp = Yb + row*64 + g*8;
  ushort4 o1, o2;
  o1.x=f2b(yout[0]); o1.y=f2b(yout[1]); o1.z=f2b(yout[2]); o1.w=f2b(yout[3]);
  o2.x=f2b(yout[4]); o2.y=f2b(yout[5]); o2.z=f2b(yout[6]); o2.w=f2b(yout[7]);
  *(ushort4*)yp = o1;
  *(ushort4*)(yp+4) = o2;
}

// ---------------- Kernel 6: output projection — 8-way col split ----------------
__global__ __launch_bounds__(64,4) void k_outproj3(
    const u16* __restrict__ Yb, const u16* __restrict__ WoF, void* __restrict__ outv,
    const int* __restrict__ fl)
{
  const int f32 = fl[0];
  const int rows0 = blockIdx.x*32;
  const int nt0 = blockIdx.y*8;
  const int lane = threadIdx.x;
  const int quad = lane>>4, l16 = lane&15;

  f32x4 acc[16];
  #pragma unroll
  for (int i=0;i<16;i++) acc[i] = (f32x4){0.f,0.f,0.f,0.f};

  #pragma unroll
  for (int ks=0;ks<2;ks++){
    int ko = ks*32 + quad*8;
    bf16x8 a0 = *(const bf16x8*)(Yb + (size_t)(rows0 + l16)*DH_ + ko);
    bf16x8 a1 = *(const bf16x8*)(Yb + (size_t)(rows0 + 16 + l16)*DH_ + ko);
    #pragma unroll
    for (int nt=0;nt<8;nt++){
      bf16x8 b = *(const bf16x8*)(WoF + ((size_t)(ks*64 + nt0 + nt)*64 + lane)*8);
      acc[nt]   = __builtin_amdgcn_mfma_f32_16x16x32_bf16(a0,b,acc[nt],0,0,0);
      acc[8+nt] = __builtin_amdgcn_mfma_f32_16x16x32_bf16(a1,b,acc[8+nt],0,0,0);
    }
  }
  #pragma unroll
  for (int sp=0;sp<2;sp++){
    #pragma unroll
    for (int nt=0;nt<8;nt++){
      #pragma unroll
      for (int i=0;i<4;i++){
        int row = rows0 + sp*16 + quad*4 + i;
        int col = (nt0+nt)*16 + l16;
        size_t idx = (size_t)row*DM_ + col;
        float v = acc[sp*8+nt][i];
        if (f32) ((float*)outv)[idx] = v;
        else ((u16*)outv)[idx] = f2b(v);
      }
    }
  }
}

extern "C" void kernel_launch(void* const* d_in, const int* in_sizes, int n_in,
                              void* d_out, int out_size, void* d_ws, size_t ws_size,
                              hipStream_t stream) {
  const void* x  = d_in[0];
  const void* Wq = d_in[1];
  const void* Wk = d_in[2];
  const void* Wv = d_in[3];
  const void* Wo = d_in[4];
  const void* UL[4] = {d_in[5],d_in[6],d_in[7],d_in[8]};
  const void* VR[4] = {d_in[9],d_in[10],d_in[11],d_in[12]};
  const void* UR[4] = {d_in[13],d_in[14],d_in[15],d_in[16]};
  const void* VL[4] = {d_in[17],d_in[18],d_in[19],d_in[20]};

  int* flag = (int*)d_ws;
  float* ws = (float*)d_ws + 16;
  float* q    = ws;
  float* kf   = q    + (size_t)BT_*64;
  float* vf   = kf   + (size_t)BT_*64;
  float* uLa  = vf   + (size_t)BT_*64;
  float* vRa  = uLa  + (size_t)BT_*88;
  float* vrxa = vRa  + (size_t)BT_*88;
  float* vlxa = vrxa + (size_t)BT_*88;
  float* SL   = vlxa + (size_t)BT_*88;
  float* SP   = SL   + (size_t)B_*NCH_*STATE_;
  u16*   Yb   = (u16*)(SP + (size_t)B_*NCH_*STATE_);
  u16*   WF   = Yb  + (size_t)BT_*64;
  u16*   WoF  = WF  + (size_t)196608;
  u16*   PF   = WoF + (size_t)65536;
  u16*   qb16 = PF  + (size_t)18432;
  u16*   kb16 = qb16 + (size_t)BT_*64;
  u16*   vb16 = kb16 + (size_t)BT_*64;

  k_detect<<<1, 64, 0, stream>>>((const u16*)x, flag);
  k_wfrag<<<137, 256, 0, stream>>>(Wq, Wk, Wv, Wo,
      UL[0],UL[1],UL[2],UL[3], VR[0],VR[1],VR[2],VR[3], VL[0],VL[1],VL[2],VL[3],
      WF, WoF, PF, flag);
  k_proj6<<<BT_/16, 768, 0, stream>>>(x, WF, q, kf, vf, qb16, kb16, vb16, flag);
  k_prep3<<<dim3(BT_/16, 4), 64, 0, stream>>>(qb16, kb16, vb16, PF, uLa, vRa, vrxa, vlxa);
  k_chunksum<<<B_*NCH_, 256, 0, stream>>>(kf, vf, uLa, vRa, SL);
  k_prefix<<<B_, 256, 0, stream>>>(SL, SP);
  k_intra<<<B_*NCH_, 256, 0, stream>>>(q, kf, vf, uLa, vRa, vrxa, vlxa, SP,
      UL[0],UL[1],UL[2],UL[3], UR[0],UR[1],UR[2],UR[3], Yb, flag);
  k_outproj3<<<dim3(512, 8), 64, 0, stream>>>(Yb, WoF, d_out, flag);
}

// Round 5
// 265.745 us; speedup vs baseline: 1.0509x; 1.0452x over previous
//
#include <hip/hip_runtime.h>
#include <hip/hip_bf16.h>

typedef unsigned short u16;
typedef __attribute__((ext_vector_type(8))) short bf16x8;
typedef __attribute__((ext_vector_type(4))) float f32x4;

#define B_ 8
#define T_ 2048
#define BT_ (B_*T_)
#define DM_ 1024
#define DH_ 64
#define NCH_ 64            // chunks per batch
#define S_ (T_/NCH_)       // 32 steps per chunk
#define STATE_ 896         // leaf 256 + Ws 576 + z 64

__device__ __forceinline__ float b2f(u16 u){ unsigned v=((unsigned)u)<<16; float f; __builtin_memcpy(&f,&v,4); return f; }
__device__ __forceinline__ u16 f2b(float f){ __hip_bfloat16 h=__float2bfloat16(f); u16 u; __builtin_memcpy(&u,&h,2); return u; }

__device__ __forceinline__ float ldin(const void* p, size_t i, int f32){
  return f32 ? ((const float*)p)[i] : b2f(((const u16*)p)[i]);
}
// load 8 consecutive elements as bf16x8 (converting from fp32 if needed)
__device__ __forceinline__ bf16x8 ld8bf(const void* p, size_t i, int f32){
  if (f32){
    f32x4 v0 = *(const f32x4*)((const float*)p + i);
    f32x4 v1 = *(const f32x4*)((const float*)p + i + 4);
    bf16x8 r;
    #pragma unroll
    for (int j=0;j<4;j++){ r[j] = (short)f2b(v0[j]); r[4+j] = (short)f2b(v1[j]); }
    return r;
  }
  return *(const bf16x8*)((const u16*)p + i);
}

// async global->LDS, 16B per lane
__device__ __forceinline__ void gl_lds16(const void* g, void* l){
  __builtin_amdgcn_global_load_lds((const __attribute__((address_space(1))) unsigned int*)g,
                                   (__attribute__((address_space(3))) unsigned int*)l, 16, 0, 0);
}

// state layout: leaf [0,256): n*16+i*4+j ; Ws: L0@256, L1@384, L2@640, L3@768 ; z@832
__device__ __forceinline__ void decodeWs(int e, int& ia, int& ib){
  if (e<384){ int o=e-256, n=o>>4; ia=n*4+((o>>2)&3); ib=n*4+(o&3); }
  else if (e<640){ int o=e-384, n=o>>6; ia=32+n*8+((o>>3)&7); ib=32+n*8+(o&7); }
  else if (e<768){ int o=e-640, n=o>>6; ia=64+n*8+((o>>3)&7); ib=64+n*8+(o&7); }
  else { int o=e-768; ia=80+((o>>3)&7); ib=80+(o&7); }
}
__device__ __forceinline__ void decode88(int f, int& l, int& n, int& ri){
  if (f<32){ l=0; n=f>>2; ri=f&3; }
  else if (f<64){ l=1; n=(f-32)>>3; ri=f&7; }
  else if (f<80){ l=2; n=(f-64)>>3; ri=f&7; }
  else { l=3; n=0; ri=f&7; }
}

// ---------------- Kernel 0: dtype detection ----------------
__global__ __launch_bounds__(64) void k_detect(const u16* __restrict__ x, int* __restrict__ flag){
  int tid = threadIdx.x;
  int sane = 0;
  for (int i = tid; i < 4096; i += 64){
    u16 u = x[i];
    int e = (u >> 7) & 0xFF;
    if ((u & 0x7FFF) == 0 || (e >= 100 && e <= 140)) sane++;
  }
  #pragma unroll
  for (int o = 32; o > 0; o >>= 1) sane += __shfl_down(sane, o);
  if (tid == 0) flag[0] = (sane < 3600) ? 1 : 0;
}

// ---------------- Kernel 0c: weight/basis -> MFMA B-fragment layout (bf16) ------
__global__ __launch_bounds__(256) void k_wfrag(
    const void* __restrict__ Wq, const void* __restrict__ Wk, const void* __restrict__ Wv,
    const void* __restrict__ Wo,
    const void* __restrict__ UL0, const void* __restrict__ UL1, const void* __restrict__ UL2, const void* __restrict__ UL3,
    const void* __restrict__ VR0, const void* __restrict__ VR1, const void* __restrict__ VR2, const void* __restrict__ VR3,
    const void* __restrict__ VL0, const void* __restrict__ VL1, const void* __restrict__ VL2, const void* __restrict__ VL3,
    u16* __restrict__ WF, u16* __restrict__ WoF, u16* __restrict__ PF,
    const int* __restrict__ fl)
{
  const int f32 = fl[0];
  int e = blockIdx.x*256 + threadIdx.x;
  if (e < 24576){
    int m = e >> 13;
    int rem = e & 8191;
    int ks = rem >> 8;
    int nt = (rem >> 6) & 3;
    int lane = rem & 63;
    const void* W = (m==0)?Wq:((m==1)?Wk:Wv);
    int kr = ks*32 + (lane>>4)*8;
    int col = nt*16 + (lane&15);
    u16 o[8];
    #pragma unroll
    for (int j=0;j<8;j++) o[j] = f2b(ldin(W, (size_t)(kr+j)*DH_ + col, f32));
    u16* dst = WF + (size_t)e*8;
    #pragma unroll
    for (int j=0;j<8;j++) dst[j] = o[j];
  } else if (e < 32768){
    int eo = e - 24576;
    int ks = eo >> 12;
    int nt = (eo >> 6) & 63;
    int lane = eo & 63;
    int kr = ks*32 + (lane>>4)*8;
    int col = nt*16 + (lane&15);
    u16 o[8];
    #pragma unroll
    for (int j=0;j<8;j++) o[j] = f2b(ldin(Wo, (size_t)(kr+j)*DM_ + col, f32));
    u16* dst = WoF + (size_t)eo*8;
    #pragma unroll
    for (int j=0;j<8;j++) dst[j] = o[j];
  } else if (e < 35072){
    int pe = e - 32768;         // 0..2303
    int lane = pe & 63;
    int nt = (pe >> 6) % 6;
    int mk = pe / 384;          // mat*2+ks
    int ks = mk & 1, mat = mk >> 1;
    int col = nt*16 + (lane&15);
    int dbase = ks*32 + (lane>>4)*8;
    const int BSl[4]={4,8,16,32}; const int Rl[4]={4,8,8,8};
    u16 o[8];
    #pragma unroll
    for (int j=0;j<8;j++){
      float val = 0.f;
      if (col < 88){
        int l,n,ri; decode88(col,l,n,ri);
        int bs=BSl[l], r=Rl[l];
        int lo = n*2*bs + ((mat==1)?bs:0);
        int d = dbase + j;
        if (d >= lo && d < lo+bs){
          const void* Up;
          if (mat==0)      Up = (l==0)?UL0:(l==1)?UL1:(l==2)?UL2:UL3;
          else if (mat==1) Up = (l==0)?VR0:(l==1)?VR1:(l==2)?VR2:VR3;
          else             Up = (l==0)?VL0:(l==1)?VL1:(l==2)?VL2:VL3;
          val = ldin(Up, (size_t)(d-lo)*r + ri, f32);
        }
      }
      o[j] = f2b(val);
    }
    u16* dst = PF + (size_t)pe*8;
    #pragma unroll
    for (int j=0;j<8;j++) dst[j] = o[j];
  }
}

// ---------------- Kernel 1: QKV projection — weight-amortized tiled GEMM ----------
// Diagnosis of r1-r4 plateau: every 16-row block re-read ALL of WF (384 KB) from
// L2 -> 393 MB L2 traffic @ ~7 TB/s = the observed ~55 us. Fix: 64-row blocks,
// grid 256, WF staged per-K-step into double-buffered LDS (each weight byte
// crosses L2 once per block: 98 MB total, 4x cut). 8 waves = 4 row-groups x
// 2 K-halves; x loaded straight to regs (1 KB/wave/step, prefetched 1 ahead).
__global__ __launch_bounds__(512, 4) void k_proj7(
    const void* __restrict__ x, const u16* __restrict__ WF,
    float* __restrict__ oq, float* __restrict__ ok_, float* __restrict__ ov,
    u16* __restrict__ qb16, u16* __restrict__ kb16, u16* __restrict__ vb16,
    const int* __restrict__ fl)
{
  __shared__ __align__(16) char sh[49152];   // 2 x 24 KB stage bufs; aliased as 48 KB reduction
  const int f32 = fl[0];
  const int tid = threadIdx.x;
  const int wv = tid>>6;          // 0..7
  const int mg = wv>>1;           // row group 0..3 (16 rows each)
  const int h  = wv&1;            // K half (16 ks-steps each)
  const int lane = tid&63;
  const int quad = lane>>4, l16 = lane&15;
  const int rows0 = blockIdx.x*64 + mg*16;
  const size_t rowA = (size_t)(rows0 + l16)*DM_;

  f32x4 acc[12];
  #pragma unroll
  for (int i=0;i<12;i++) acc[i] = (f32x4){0.f,0.f,0.f,0.f};

  // stage the 24 fragments (12 per K-half) of step t into buffer buf
  // frag slot s = wv + r*8 (r=0..2): hs = s/12, f = s%12 (m=f>>2, nt=f&3)
  #define STAGE(t, buf) do{                                                   \
    _Pragma("unroll")                                                         \
    for (int r=0;r<3;r++){                                                    \
      int s = wv + r*8;                                                       \
      int hs = (s>=12) ? 1 : 0;                                               \
      int f = s - hs*12;                                                      \
      int m_ = f>>2, nt_ = f&3;                                               \
      int ks_ = hs*16 + (t);                                                  \
      const char* src = (const char*)WF + (size_t)((m_*32+ks_)*4+nt_)*1024 + (size_t)lane*16; \
      char* dst = sh + (buf)*24576 + hs*12288 + f*1024 + lane*16;             \
      gl_lds16(src, dst);                                                     \
    } }while(0)

  STAGE(0, 0);
  bf16x8 a_cur = ld8bf(x, rowA + (size_t)(h*16)*32 + quad*8, f32);
  asm volatile("s_waitcnt vmcnt(0)" ::: "memory");
  __syncthreads();

  bf16x8 a_nxt = a_cur;
  for (int t=0;t<16;t++){
    int buf = t&1;
    if (t<15){
      STAGE(t+1, buf^1);
      a_nxt = ld8bf(x, rowA + (size_t)(h*16+t+1)*32 + quad*8, f32);
    }
    const char* bb = sh + buf*24576 + h*12288;
    #pragma unroll
    for (int f=0;f<12;f++){
      bf16x8 b = *(const bf16x8*)(bb + f*1024 + lane*16);
      acc[f] = __builtin_amdgcn_mfma_f32_16x16x32_bf16(a_cur, b, acc[f],0,0,0);
    }
    a_cur = a_nxt;
    asm volatile("s_waitcnt vmcnt(0)" ::: "memory");
    __syncthreads();
  }
  #undef STAGE

  // cross-K-half reduction through LDS (stage buffers are dead now)
  if (h==1){
    #pragma unroll
    for (int i=0;i<12;i++) ((f32x4*)sh)[(mg*12+i)*64 + lane] = acc[i];
  }
  __syncthreads();
  if (h==0){
    #pragma unroll
    for (int i=0;i<12;i++){
      f32x4 r = ((f32x4*)sh)[(mg*12+i)*64 + lane];
      acc[i][0]+=r[0]; acc[i][1]+=r[1]; acc[i][2]+=r[2]; acc[i][3]+=r[3];
    }
    #pragma unroll
    for (int m=0;m<3;m++){
      float* __restrict__ outp = (m==0)?oq:((m==1)?ok_:ov);
      u16* __restrict__ outb = (m==0)?qb16:((m==1)?kb16:vb16);
      #pragma unroll
      for (int nt=0;nt<4;nt++){
        #pragma unroll
        for (int i=0;i<4;i++){
          int row = rows0 + quad*4 + i;
          int col = nt*16 + l16;
          float val = acc[m*4+nt][i];
          if (m<2) val = (val>0.f)? (val+1.f) : expf(val);  // elu1
          outp[(size_t)row*DH_ + col] = val;
          outb[(size_t)row*DH_ + col] = f2b(val);
        }
      }
    }
  }
}

// ---------------- Kernel 2: basis projections via MFMA — per-matrix split --------
__global__ __launch_bounds__(64) void k_prep3(
    const u16* __restrict__ qb16, const u16* __restrict__ kb16, const u16* __restrict__ vb16,
    const u16* __restrict__ PF,
    float* __restrict__ uLa, float* __restrict__ vRa, float* __restrict__ vrxa, float* __restrict__ vlxa)
{
  const int m = blockIdx.y;          // 0:uL=K@Mu 1:vR=V@Mv 2:vrx=Q@Mv 3:vlx=Q@Mlx
  const int rows0 = blockIdx.x*16;
  const int lane = threadIdx.x;
  const int quad = lane>>4, l16 = lane&15;

  const u16* __restrict__ src = (m==0)?kb16:((m==1)?vb16:qb16);
  const int mat = (m==0)?0:((m==3)?2:1);   // PF matrix index {Mu,Mv,Mlx}

  bf16x8 a[2];
  #pragma unroll
  for (int ks=0;ks<2;ks++){
    size_t off = (size_t)(rows0 + l16)*DH_ + ks*32 + quad*8;
    a[ks] = *(const bf16x8*)(src + off);
  }
  f32x4 acc[6];
  #pragma unroll
  for (int nt=0;nt<6;nt++) acc[nt] = (f32x4){0.f,0.f,0.f,0.f};

  #pragma unroll
  for (int ks=0;ks<2;ks++){
    #pragma unroll
    for (int nt=0;nt<6;nt++){
      bf16x8 b = *(const bf16x8*)(PF + ((size_t)((mat*2+ks)*6+nt)*64 + lane)*8);
      acc[nt] = __builtin_amdgcn_mfma_f32_16x16x32_bf16(a[ks], b, acc[nt],0,0,0);
    }
  }
  float* __restrict__ dst = (m==0)?uLa:(m==1)?vRa:(m==2)?vrxa:vlxa;
  #pragma unroll
  for (int nt=0;nt<6;nt++){
    int col = nt*16 + l16;
    if (col < 88){
      #pragma unroll
      for (int i=0;i<4;i++){
        int row = rows0 + quad*4 + i;
        dst[(size_t)row*88 + col] = acc[nt][i];
      }
    }
  }
}

// ---------------- Kernel 3: per-chunk state sums ----------------
__global__ __launch_bounds__(256) void k_chunksum(
    const float* __restrict__ gk, const float* __restrict__ gv,
    const float* __restrict__ uLa, const float* __restrict__ vRa,
    float* __restrict__ SL)
{
  const int bid = blockIdx.x;
  const int b = bid/NCH_, c = bid%NCH_;
  const size_t base64 = (size_t)(b*T_ + c*S_)*64;
  const size_t base88 = (size_t)(b*T_ + c*S_)*88;
  for (int p=0;p<4;p++){
    int e = threadIdx.x + p*256;
    if (e>=STATE_) break;
    float acc=0.f;
    if (e < 256){
      int n=e>>4;
      const float* A = gk + base64 + n*4 + ((e>>2)&3);
      const float* Bp = gv + base64 + n*4 + (e&3);
      for (int s=0;s<S_;s++) acc += A[s*64]*Bp[s*64];
    } else if (e < 832){
      int ia, ib; decodeWs(e, ia, ib);
      const float* A = uLa + base88 + ia;
      const float* Bp = vRa + base88 + ib;
      for (int s=0;s<S_;s++) acc += A[s*88]*Bp[s*88];
    } else {
      const float* A = gk + base64 + (e-832);
      for (int s=0;s<S_;s++) acc += A[s*64];
    }
    SL[(size_t)bid*STATE_ + e] = acc;
  }
}

// ---------------- Kernel 4: exclusive prefix over chunks ----------------
__global__ __launch_bounds__(256) void k_prefix(const float* __restrict__ SL, float* __restrict__ SP){
  const int b = blockIdx.x;
  for (int p=0;p<4;p++){
    int e = threadIdx.x + p*256;
    if (e>=STATE_) break;
    float run=0.f;
    for (int c=0;c<NCH_;c++){
      size_t idx = ((size_t)(b*NCH_+c))*STATE_ + e;
      SP[idx] = run; run += SL[idx];
    }
  }
}

// ---------------- Kernel 5: parallel intra-chunk ----------------
__global__ __launch_bounds__(256) void k_intra(
    const float* __restrict__ gq, const float* __restrict__ gk, const float* __restrict__ gv,
    const float* __restrict__ uLa, const float* __restrict__ vRa,
    const float* __restrict__ vrxa, const float* __restrict__ vlxa,
    const float* __restrict__ SP,
    const void* __restrict__ UL0, const void* __restrict__ UL1, const void* __restrict__ UL2, const void* __restrict__ UL3,
    const void* __restrict__ UR0, const void* __restrict__ UR1, const void* __restrict__ UR2, const void* __restrict__ UR3,
    u16* __restrict__ Yb, const int* __restrict__ fl)
{
  __shared__ float kS[S_*64];
  __shared__ float vS[S_*64];
  __shared__ float uvS[S_*176];
  __shared__ float st0[STATE_];
  __shared__ float ULs[464], URs[464];
  const int f32 = fl[0];
  const int tid = threadIdx.x;
  const int bid = blockIdx.x;
  const int b = bid/NCH_, c = bid%NCH_;
  const int row0 = b*T_ + c*S_;

  const size_t r64 = (size_t)row0*64;
  for (int i=tid;i<S_*64;i+=256){ kS[i]=gk[r64+i]; vS[i]=gv[r64+i]; }
  const size_t r88 = (size_t)row0*88;
  for (int i=tid;i<S_*88;i+=256){
    int s=i/88, f=i-s*88;
    uvS[s*176+f]    = uLa[r88+i];
    uvS[s*176+88+f] = vRa[r88+i];
  }
  for (int e=tid;e<STATE_;e+=256) st0[e] = SP[(size_t)bid*STATE_+e];
  for (int e=tid;e<464;e+=256){
    int l, idx;
    if (e<16){ l=0; idx=e; } else if (e<80){ l=1; idx=e-16; }
    else if (e<208){ l=2; idx=e-80; } else { l=3; idx=e-208; }
    const void* ul = (l==0)?UL0:(l==1)?UL1:(l==2)?UL2:UL3;
    const void* ur = (l==0)?UR0:(l==1)?UR1:(l==2)?UR2:UR3;
    ULs[e] = ldin(ul, idx, f32); URs[e] = ldin(ur, idx, f32);
  }
  __syncthreads();

  const int w = tid>>6, lane = tid&63, tl = lane>>3, g = lane&7;
  const int t = w*8 + tl;
  const int n1 = g>>1, ri1 = (g&1)*4;
  const int n2 = g>>2, ri2 = (g&3)*2;
  const size_t row = (size_t)(row0 + t);

  float qr[8];
  { const float* qp = gq + row*64 + g*8;
    *(f32x4*)&qr[0] = *(const f32x4*)qp; *(f32x4*)&qr[4] = *(const f32x4*)(qp+4); }
  float rxL0[4], lxL0[4], rxL1[8], lxL1[8], rxL2[8], lxL2[8], rxL3[8], lxL3[8];
  { const float* rp = vrxa + row*88; const float* lp = vlxa + row*88;
    *(f32x4*)&rxL0[0] = *(const f32x4*)(rp + 4*g);
    *(f32x4*)&lxL0[0] = *(const f32x4*)(lp + 4*g);
    *(f32x4*)&rxL1[0] = *(const f32x4*)(rp + 32 + n1*8); *(f32x4*)&rxL1[4] = *(const f32x4*)(rp + 36 + n1*8);
    *(f32x4*)&lxL1[0] = *(const f32x4*)(lp + 32 + n1*8); *(f32x4*)&lxL1[4] = *(const f32x4*)(lp + 36 + n1*8);
    *(f32x4*)&rxL2[0] = *(const f32x4*)(rp + 64 + n2*8); *(f32x4*)&rxL2[4] = *(const f32x4*)(rp + 68 + n2*8);
    *(f32x4*)&lxL2[0] = *(const f32x4*)(lp + 64 + n2*8); *(f32x4*)&lxL2[4] = *(const f32x4*)(lp + 68 + n2*8);
    *(f32x4*)&rxL3[0] = *(const f32x4*)(rp + 80); *(f32x4*)&rxL3[4] = *(const f32x4*)(rp + 84);
    *(f32x4*)&lxL3[0] = *(const f32x4*)(lp + 80); *(f32x4*)&lxL3[4] = *(const f32x4*)(lp + 84); }

  float yacc[8], den = 0.f;
  #pragma unroll
  for (int cc=0;cc<8;cc++){
    int n = 2*g + (cc>>2);
    const float* m = &st0[n*16 + (cc&3)*4];
    const float* qp = &qr[(cc>>2)*4];
    yacc[cc] = m[0]*qp[0]+m[1]*qp[1]+m[2]*qp[2]+m[3]*qp[3];
    den += st0[832 + g*8 + cc]*qr[cc];
  }
  float gtL0[4], gbL0[4], gtL1[4], gbL1[4], gtL2[2], gbL2[2], gtL3, gbL3;
  #pragma unroll
  for (int cc=0;cc<4;cc++){
    const float* m = &st0[256 + g*16 + cc*4];
    gtL0[cc] = m[0]*rxL0[0]+m[1]*rxL0[1]+m[2]*rxL0[2]+m[3]*rxL0[3];
    float s2 = 0.f;
    #pragma unroll
    for (int j=0;j<4;j++) s2 += st0[256 + g*16 + j*4 + cc]*lxL0[j];
    gbL0[cc] = s2;
  }
  #pragma unroll
  for (int cc=0;cc<4;cc++){
    int ri = ri1 + cc;
    float s1=0.f, s2=0.f;
    #pragma unroll
    for (int j=0;j<8;j++){
      s1 += st0[384 + n1*64 + ri*8 + j]*rxL1[j];
      s2 += st0[384 + n1*64 + j*8 + ri]*lxL1[j];
    }
    gtL1[cc]=s1; gbL1[cc]=s2;
  }
  #pragma unroll
  for (int cc=0;cc<2;cc++){
    int ri = ri2 + cc;
    float s1=0.f, s2=0.f;
    #pragma unroll
    for (int j=0;j<8;j++){
      s1 += st0[640 + n2*64 + ri*8 + j]*rxL2[j];
      s2 += st0[640 + n2*64 + j*8 + ri]*lxL2[j];
    }
    gtL2[cc]=s1; gbL2[cc]=s2;
  }
  { float s1=0.f, s2=0.f;
    #pragma unroll
    for (int j=0;j<8;j++){
      s1 += st0[768 + g*8 + j]*rxL3[j];
      s2 += st0[768 + j*8 + g]*lxL3[j];
    }
    gtL3=s1; gbL3=s2; }

  const int smax = w*8 + 8;
  for (int s=0; s<smax; s++){
    const float* ks_ = &kS[s*64 + g*8];
    const float* vs_ = &vS[s*64 + g*8];
    const float* uL_ = &uvS[s*176];
    const float* vR_ = &uvS[s*176 + 88];
    float dv0 = vs_[0]*qr[0]+vs_[1]*qr[1]+vs_[2]*qr[2]+vs_[3]*qr[3];
    float dv1 = vs_[4]*qr[4]+vs_[5]*qr[5]+vs_[6]*qr[6]+vs_[7]*qr[7];
    float dn = 0.f;
    #pragma unroll
    for (int cc=0;cc<8;cc++) dn += ks_[cc]*qr[cc];
    float d1L0=0.f,d2L0=0.f;
    #pragma unroll
    for (int j=0;j<4;j++){ d1L0 += vR_[4*g+j]*rxL0[j]; d2L0 += uL_[4*g+j]*lxL0[j]; }
    float d1L1=0.f,d2L1=0.f;
    #pragma unroll
    for (int j=0;j<8;j++){ d1L1 += vR_[32+n1*8+j]*rxL1[j]; d2L1 += uL_[32+n1*8+j]*lxL1[j]; }
    float d1L2=0.f,d2L2=0.f;
    #pragma unroll
    for (int j=0;j<8;j++){ d1L2 += vR_[64+n2*8+j]*rxL2[j]; d2L2 += uL_[64+n2*8+j]*lxL2[j]; }
    float d1L3=0.f,d2L3=0.f;
    #pragma unroll
    for (int j=0;j<8;j++){ d1L3 += vR_[80+j]*rxL3[j]; d2L3 += uL_[80+j]*lxL3[j]; }
    if (s<=t){
      den += dn;
      #pragma unroll
      for (int cc=0;cc<8;cc++) yacc[cc] += ks_[cc]*((cc<4)?dv0:dv1);
      #pragma unroll
      for (int cc=0;cc<4;cc++){
        gtL0[cc] += uL_[4*g+cc]*d1L0;          gbL0[cc] += vR_[4*g+cc]*d2L0;
        gtL1[cc] += uL_[32+n1*8+ri1+cc]*d1L1;  gbL1[cc] += vR_[32+n1*8+ri1+cc]*d2L1;
      }
      #pragma unroll
      for (int cc=0;cc<2;cc++){
        gtL2[cc] += uL_[64+n2*8+ri2+cc]*d1L2;  gbL2[cc] += vR_[64+n2*8+ri2+cc]*d2L2;
      }
      gtL3 += uL_[80+g]*d1L3;  gbL3 += vR_[80+g]*d2L3;
    }
  }
  __syncthreads();

  { float* gr = &uvS[t*176];
    #pragma unroll
    for (int cc=0;cc<4;cc++){
      gr[4*g+cc] = gtL0[cc];                 gr[88+4*g+cc] = gbL0[cc];
      gr[32+n1*8+ri1+cc] = gtL1[cc];         gr[88+32+n1*8+ri1+cc] = gbL1[cc];
    }
    #pragma unroll
    for (int cc=0;cc<2;cc++){
      gr[64+n2*8+ri2+cc] = gtL2[cc];         gr[88+64+n2*8+ri2+cc] = gbL2[cc];
    }
    gr[80+g] = gtL3;  gr[88+80+g] = gbL3;
  }
  __syncthreads();

  den += __shfl_xor(den,1); den += __shfl_xor(den,2); den += __shfl_xor(den,4);
  float inv = 1.f / fmaxf(den, 1e-6f);
  const float* gr = &uvS[t*176];
  float yout[8];
  #pragma unroll
  for (int cc=0;cc<8;cc++){
    int j = g*8 + cc;
    float y = yacc[cc];
    if (cc<4){
      #pragma unroll
      for (int rr=0;rr<4;rr++) y += ULs[cc*4+rr]*gr[g*4+rr];
    } else {
      #pragma unroll
      for (int rr=0;rr<4;rr++) y += URs[(cc-4)*4+rr]*gr[88+g*4+rr];
    }
    { int seg=j>>4, pos=j&15;
      if (pos<8){
        #pragma unroll
        for (int rr=0;rr<8;rr++) y += ULs[16+pos*8+rr]*gr[32+seg*8+rr];
      } else {
        #pragma unroll
        for (int rr=0;rr<8;rr++) y += URs[16+(pos-8)*8+rr]*gr[88+32+seg*8+rr];
      } }
    { int seg=j>>5, pos=j&31;
      if (pos<16){
        #pragma unroll
        for (int rr=0;rr<8;rr++) y += ULs[80+pos*8+rr]*gr[64+seg*8+rr];
      } else {
        #pragma unroll
        for (int rr=0;rr<8;rr++) y += URs[80+(pos-16)*8+rr]*gr[88+64+seg*8+rr];
      } }
    { int pos=j;
      if (pos<32){
        #pragma unroll
        for (int rr=0;rr<8;rr++) y += ULs[208+pos*8+rr]*gr[80+rr];
      } else {
        #pragma unroll
        for (int rr=0;rr<8;rr++) y += URs[208+(pos-32)*8+rr]*gr[88+80+rr];
      } }
    yout[cc] = y*inv;
  }
  u16* yp = Yb + row*64 + g*8;
  ushort4 o1, o2;
  o1.x=f2b(yout[0]); o1.y=f2b(yout[1]); o1.z=f2b(yout[2]); o1.w=f2b(yout[3]);
  o2.x=f2b(yout[4]); o2.y=f2b(yout[5]); o2.z=f2b(yout[6]); o2.w=f2b(yout[7]);
  *(ushort4*)yp = o1;
  *(ushort4*)(yp+4) = o2;
}

// ---------------- Kernel 6: output projection — 8-way col split ----------------
__global__ __launch_bounds__(64,4) void k_outproj3(
    const u16* __restrict__ Yb, const u16* __restrict__ WoF, void* __restrict__ outv,
    const int* __restrict__ fl)
{
  const int f32 = fl[0];
  const int rows0 = blockIdx.x*32;
  const int nt0 = blockIdx.y*8;
  const int lane = threadIdx.x;
  const int quad = lane>>4, l16 = lane&15;

  f32x4 acc[16];
  #pragma unroll
  for (int i=0;i<16;i++) acc[i] = (f32x4){0.f,0.f,0.f,0.f};

  #pragma unroll
  for (int ks=0;ks<2;ks++){
    int ko = ks*32 + quad*8;
    bf16x8 a0 = *(const bf16x8*)(Yb + (size_t)(rows0 + l16)*DH_ + ko);
    bf16x8 a1 = *(const bf16x8*)(Yb + (size_t)(rows0 + 16 + l16)*DH_ + ko);
    #pragma unroll
    for (int nt=0;nt<8;nt++){
      bf16x8 b = *(const bf16x8*)(WoF + ((size_t)(ks*64 + nt0 + nt)*64 + lane)*8);
      acc[nt]   = __builtin_amdgcn_mfma_f32_16x16x32_bf16(a0,b,acc[nt],0,0,0);
      acc[8+nt] = __builtin_amdgcn_mfma_f32_16x16x32_bf16(a1,b,acc[8+nt],0,0,0);
    }
  }
  #pragma unroll
  for (int sp=0;sp<2;sp++){
    #pragma unroll
    for (int nt=0;nt<8;nt++){
      #pragma unroll
      for (int i=0;i<4;i++){
        int row = rows0 + sp*16 + quad*4 + i;
        int col = (nt0+nt)*16 + l16;
        size_t idx = (size_t)row*DM_ + col;
        float v = acc[sp*8+nt][i];
        if (f32) ((float*)outv)[idx] = v;
        else ((u16*)outv)[idx] = f2b(v);
      }
    }
  }
}

extern "C" void kernel_launch(void* const* d_in, const int* in_sizes, int n_in,
                              void* d_out, int out_size, void* d_ws, size_t ws_size,
                              hipStream_t stream) {
  const void* x  = d_in[0];
  const void* Wq = d_in[1];
  const void* Wk = d_in[2];
  const void* Wv = d_in[3];
  const void* Wo = d_in[4];
  const void* UL[4] = {d_in[5],d_in[6],d_in[7],d_in[8]};
  const void* VR[4] = {d_in[9],d_in[10],d_in[11],d_in[12]};
  const void* UR[4] = {d_in[13],d_in[14],d_in[15],d_in[16]};
  const void* VL[4] = {d_in[17],d_in[18],d_in[19],d_in[20]};

  int* flag = (int*)d_ws;
  float* ws = (float*)d_ws + 16;
  float* q    = ws;
  float* kf   = q    + (size_t)BT_*64;
  float* vf   = kf   + (size_t)BT_*64;
  float* uLa  = vf   + (size_t)BT_*64;
  float* vRa  = uLa  + (size_t)BT_*88;
  float* vrxa = vRa  + (size_t)BT_*88;
  float* vlxa = vrxa + (size_t)BT_*88;
  float* SL   = vlxa + (size_t)BT_*88;
  float* SP   = SL   + (size_t)B_*NCH_*STATE_;
  u16*   Yb   = (u16*)(SP + (size_t)B_*NCH_*STATE_);
  u16*   WF   = Yb  + (size_t)BT_*64;
  u16*   WoF  = WF  + (size_t)196608;
  u16*   PF   = WoF + (size_t)65536;
  u16*   qb16 = PF  + (size_t)18432;
  u16*   kb16 = qb16 + (size_t)BT_*64;
  u16*   vb16 = kb16 + (size_t)BT_*64;

  k_detect<<<1, 64, 0, stream>>>((const u16*)x, flag);
  k_wfrag<<<137, 256, 0, stream>>>(Wq, Wk, Wv, Wo,
      UL[0],UL[1],UL[2],UL[3], VR[0],VR[1],VR[2],VR[3], VL[0],VL[1],VL[2],VL[3],
      WF, WoF, PF, flag);
  k_proj7<<<BT_/64, 512, 0, stream>>>(x, WF, q, kf, vf, qb16, kb16, vb16, flag);
  k_prep3<<<dim3(BT_/16, 4), 64, 0, stream>>>(qb16, kb16, vb16, PF, uLa, vRa, vrxa, vlxa);
  k_chunksum<<<B_*NCH_, 256, 0, stream>>>(kf, vf, uLa, vRa, SL);
  k_prefix<<<B_, 256, 0, stream>>>(SL, SP);
  k_intra<<<B_*NCH_, 256, 0, stream>>>(q, kf, vf, uLa, vRa, vrxa, vlxa, SP,
      UL[0],UL[1],UL[2],UL[3], UR[0],UR[1],UR[2],UR[3], Yb, flag);
  k_outproj3<<<dim3(512, 8), 64, 0, stream>>>(Yb, WoF, d_out, flag);
}

// Round 6
// 242.328 us; speedup vs baseline: 1.1525x; 1.0966x over previous
//
#include <hip/hip_runtime.h>
#include <hip/hip_bf16.h>

typedef unsigned short u16;
typedef __attribute__((ext_vector_type(8))) short bf16x8;
typedef __attribute__((ext_vector_type(4))) float f32x4;

#define B_ 8
#define T_ 2048
#define BT_ (B_*T_)
#define DM_ 1024
#define DH_ 64
#define NCH_ 128           // chunks per batch (r6: 64->128, halves intra s-loop)
#define S_ (T_/NCH_)       // 16 steps per chunk
#define STATE_ 896         // leaf 256 + Ws 576 + z 64
#define UVP 180            // padded uvS row stride (176 + 4): odd bank spread

__device__ __forceinline__ float b2f(u16 u){ unsigned v=((unsigned)u)<<16; float f; __builtin_memcpy(&f,&v,4); return f; }
__device__ __forceinline__ u16 f2b(float f){ __hip_bfloat16 h=__float2bfloat16(f); u16 u; __builtin_memcpy(&u,&h,2); return u; }

__device__ __forceinline__ float ldin(const void* p, size_t i, int f32){
  return f32 ? ((const float*)p)[i] : b2f(((const u16*)p)[i]);
}
// load 8 consecutive elements as bf16x8 (converting from fp32 if needed)
__device__ __forceinline__ bf16x8 ld8bf(const void* p, size_t i, int f32){
  if (f32){
    f32x4 v0 = *(const f32x4*)((const float*)p + i);
    f32x4 v1 = *(const f32x4*)((const float*)p + i + 4);
    bf16x8 r;
    #pragma unroll
    for (int j=0;j<4;j++){ r[j] = (short)f2b(v0[j]); r[4+j] = (short)f2b(v1[j]); }
    return r;
  }
  return *(const bf16x8*)((const u16*)p + i);
}

// async global->LDS, 16B per lane
__device__ __forceinline__ void gl_lds16(const void* g, void* l){
  __builtin_amdgcn_global_load_lds((const __attribute__((address_space(1))) unsigned int*)g,
                                   (__attribute__((address_space(3))) unsigned int*)l, 16, 0, 0);
}

// state layout: leaf [0,256): n*16+i*4+j ; Ws: L0@256, L1@384, L2@640, L3@768 ; z@832
__device__ __forceinline__ void decodeWs(int e, int& ia, int& ib){
  if (e<384){ int o=e-256, n=o>>4; ia=n*4+((o>>2)&3); ib=n*4+(o&3); }
  else if (e<640){ int o=e-384, n=o>>6; ia=32+n*8+((o>>3)&7); ib=32+n*8+(o&7); }
  else if (e<768){ int o=e-640, n=o>>6; ia=64+n*8+((o>>3)&7); ib=64+n*8+(o&7); }
  else { int o=e-768; ia=80+((o>>3)&7); ib=80+(o&7); }
}
__device__ __forceinline__ void decode88(int f, int& l, int& n, int& ri){
  if (f<32){ l=0; n=f>>2; ri=f&3; }
  else if (f<64){ l=1; n=(f-32)>>3; ri=f&7; }
  else if (f<80){ l=2; n=(f-64)>>3; ri=f&7; }
  else { l=3; n=0; ri=f&7; }
}

// ---------------- Kernel 0: dtype detection ----------------
__global__ __launch_bounds__(64) void k_detect(const u16* __restrict__ x, int* __restrict__ flag){
  int tid = threadIdx.x;
  int sane = 0;
  for (int i = tid; i < 4096; i += 64){
    u16 u = x[i];
    int e = (u >> 7) & 0xFF;
    if ((u & 0x7FFF) == 0 || (e >= 100 && e <= 140)) sane++;
  }
  #pragma unroll
  for (int o = 32; o > 0; o >>= 1) sane += __shfl_down(sane, o);
  if (tid == 0) flag[0] = (sane < 3600) ? 1 : 0;
}

// ---------------- Kernel 0c: weight/basis -> MFMA B-fragment layout (bf16) ------
__global__ __launch_bounds__(256) void k_wfrag(
    const void* __restrict__ Wq, const void* __restrict__ Wk, const void* __restrict__ Wv,
    const void* __restrict__ Wo,
    const void* __restrict__ UL0, const void* __restrict__ UL1, const void* __restrict__ UL2, const void* __restrict__ UL3,
    const void* __restrict__ VR0, const void* __restrict__ VR1, const void* __restrict__ VR2, const void* __restrict__ VR3,
    const void* __restrict__ VL0, const void* __restrict__ VL1, const void* __restrict__ VL2, const void* __restrict__ VL3,
    u16* __restrict__ WF, u16* __restrict__ WoF, u16* __restrict__ PF,
    const int* __restrict__ fl)
{
  const int f32 = fl[0];
  int e = blockIdx.x*256 + threadIdx.x;
  if (e < 24576){
    int m = e >> 13;
    int rem = e & 8191;
    int ks = rem >> 8;
    int nt = (rem >> 6) & 3;
    int lane = rem & 63;
    const void* W = (m==0)?Wq:((m==1)?Wk:Wv);
    int kr = ks*32 + (lane>>4)*8;
    int col = nt*16 + (lane&15);
    u16 o[8];
    #pragma unroll
    for (int j=0;j<8;j++) o[j] = f2b(ldin(W, (size_t)(kr+j)*DH_ + col, f32));
    u16* dst = WF + (size_t)e*8;
    #pragma unroll
    for (int j=0;j<8;j++) dst[j] = o[j];
  } else if (e < 32768){
    int eo = e - 24576;
    int ks = eo >> 12;
    int nt = (eo >> 6) & 63;
    int lane = eo & 63;
    int kr = ks*32 + (lane>>4)*8;
    int col = nt*16 + (lane&15);
    u16 o[8];
    #pragma unroll
    for (int j=0;j<8;j++) o[j] = f2b(ldin(Wo, (size_t)(kr+j)*DM_ + col, f32));
    u16* dst = WoF + (size_t)eo*8;
    #pragma unroll
    for (int j=0;j<8;j++) dst[j] = o[j];
  } else if (e < 35072){
    int pe = e - 32768;         // 0..2303
    int lane = pe & 63;
    int nt = (pe >> 6) % 6;
    int mk = pe / 384;          // mat*2+ks
    int ks = mk & 1, mat = mk >> 1;
    int col = nt*16 + (lane&15);
    int dbase = ks*32 + (lane>>4)*8;
    const int BSl[4]={4,8,16,32}; const int Rl[4]={4,8,8,8};
    u16 o[8];
    #pragma unroll
    for (int j=0;j<8;j++){
      float val = 0.f;
      if (col < 88){
        int l,n,ri; decode88(col,l,n,ri);
        int bs=BSl[l], r=Rl[l];
        int lo = n*2*bs + ((mat==1)?bs:0);
        int d = dbase + j;
        if (d >= lo && d < lo+bs){
          const void* Up;
          if (mat==0)      Up = (l==0)?UL0:(l==1)?UL1:(l==2)?UL2:UL3;
          else if (mat==1) Up = (l==0)?VR0:(l==1)?VR1:(l==2)?VR2:VR3;
          else             Up = (l==0)?VL0:(l==1)?VL1:(l==2)?VL2:VL3;
          val = ldin(Up, (size_t)(d-lo)*r + ri, f32);
        }
      }
      o[j] = f2b(val);
    }
    u16* dst = PF + (size_t)pe*8;
    #pragma unroll
    for (int j=0;j<8;j++) dst[j] = o[j];
  }
}

// ---------------- Kernel 1: QKV projection — weight-amortized tiled GEMM ----------
__global__ __launch_bounds__(512, 4) void k_proj7(
    const void* __restrict__ x, const u16* __restrict__ WF,
    float* __restrict__ oq, float* __restrict__ ok_, float* __restrict__ ov,
    u16* __restrict__ qb16, u16* __restrict__ kb16, u16* __restrict__ vb16,
    const int* __restrict__ fl)
{
  __shared__ __align__(16) char sh[49152];   // 2 x 24 KB stage bufs; aliased as 48 KB reduction
  const int f32 = fl[0];
  const int tid = threadIdx.x;
  const int wv = tid>>6;          // 0..7
  const int mg = wv>>1;           // row group 0..3 (16 rows each)
  const int h  = wv&1;            // K half (16 ks-steps each)
  const int lane = tid&63;
  const int quad = lane>>4, l16 = lane&15;
  const int rows0 = blockIdx.x*64 + mg*16;
  const size_t rowA = (size_t)(rows0 + l16)*DM_;

  f32x4 acc[12];
  #pragma unroll
  for (int i=0;i<12;i++) acc[i] = (f32x4){0.f,0.f,0.f,0.f};

  #define STAGE(t, buf) do{                                                   \
    _Pragma("unroll")                                                         \
    for (int r=0;r<3;r++){                                                    \
      int s = wv + r*8;                                                       \
      int hs = (s>=12) ? 1 : 0;                                               \
      int f = s - hs*12;                                                      \
      int m_ = f>>2, nt_ = f&3;                                               \
      int ks_ = hs*16 + (t);                                                  \
      const char* src = (const char*)WF + (size_t)((m_*32+ks_)*4+nt_)*1024 + (size_t)lane*16; \
      char* dst = sh + (buf)*24576 + hs*12288 + f*1024 + lane*16;             \
      gl_lds16(src, dst);                                                     \
    } }while(0)

  STAGE(0, 0);
  bf16x8 a_cur = ld8bf(x, rowA + (size_t)(h*16)*32 + quad*8, f32);
  asm volatile("s_waitcnt vmcnt(0)" ::: "memory");
  __syncthreads();

  bf16x8 a_nxt = a_cur;
  for (int t=0;t<16;t++){
    int buf = t&1;
    if (t<15){
      STAGE(t+1, buf^1);
      a_nxt = ld8bf(x, rowA + (size_t)(h*16+t+1)*32 + quad*8, f32);
    }
    const char* bb = sh + buf*24576 + h*12288;
    #pragma unroll
    for (int f=0;f<12;f++){
      bf16x8 b = *(const bf16x8*)(bb + f*1024 + lane*16);
      acc[f] = __builtin_amdgcn_mfma_f32_16x16x32_bf16(a_cur, b, acc[f],0,0,0);
    }
    a_cur = a_nxt;
    asm volatile("s_waitcnt vmcnt(0)" ::: "memory");
    __syncthreads();
  }
  #undef STAGE

  // cross-K-half reduction through LDS (stage buffers are dead now)
  if (h==1){
    #pragma unroll
    for (int i=0;i<12;i++) ((f32x4*)sh)[(mg*12+i)*64 + lane] = acc[i];
  }
  __syncthreads();
  if (h==0){
    #pragma unroll
    for (int i=0;i<12;i++){
      f32x4 r = ((f32x4*)sh)[(mg*12+i)*64 + lane];
      acc[i][0]+=r[0]; acc[i][1]+=r[1]; acc[i][2]+=r[2]; acc[i][3]+=r[3];
    }
    #pragma unroll
    for (int m=0;m<3;m++){
      float* __restrict__ outp = (m==0)?oq:((m==1)?ok_:ov);
      u16* __restrict__ outb = (m==0)?qb16:((m==1)?kb16:vb16);
      #pragma unroll
      for (int nt=0;nt<4;nt++){
        #pragma unroll
        for (int i=0;i<4;i++){
          int row = rows0 + quad*4 + i;
          int col = nt*16 + l16;
          float val = acc[m*4+nt][i];
          if (m<2) val = (val>0.f)? (val+1.f) : expf(val);  // elu1
          outp[(size_t)row*DH_ + col] = val;
          outb[(size_t)row*DH_ + col] = f2b(val);
        }
      }
    }
  }
}

// ---------------- Kernel 2: basis projections via MFMA — per-matrix split --------
__global__ __launch_bounds__(64) void k_prep3(
    const u16* __restrict__ qb16, const u16* __restrict__ kb16, const u16* __restrict__ vb16,
    const u16* __restrict__ PF,
    float* __restrict__ uLa, float* __restrict__ vRa, float* __restrict__ vrxa, float* __restrict__ vlxa)
{
  const int m = blockIdx.y;          // 0:uL=K@Mu 1:vR=V@Mv 2:vrx=Q@Mv 3:vlx=Q@Mlx
  const int rows0 = blockIdx.x*16;
  const int lane = threadIdx.x;
  const int quad = lane>>4, l16 = lane&15;

  const u16* __restrict__ src = (m==0)?kb16:((m==1)?vb16:qb16);
  const int mat = (m==0)?0:((m==3)?2:1);   // PF matrix index {Mu,Mv,Mlx}

  bf16x8 a[2];
  #pragma unroll
  for (int ks=0;ks<2;ks++){
    size_t off = (size_t)(rows0 + l16)*DH_ + ks*32 + quad*8;
    a[ks] = *(const bf16x8*)(src + off);
  }
  f32x4 acc[6];
  #pragma unroll
  for (int nt=0;nt<6;nt++) acc[nt] = (f32x4){0.f,0.f,0.f,0.f};

  #pragma unroll
  for (int ks=0;ks<2;ks++){
    #pragma unroll
    for (int nt=0;nt<6;nt++){
      bf16x8 b = *(const bf16x8*)(PF + ((size_t)((mat*2+ks)*6+nt)*64 + lane)*8);
      acc[nt] = __builtin_amdgcn_mfma_f32_16x16x32_bf16(a[ks], b, acc[nt],0,0,0);
    }
  }
  float* __restrict__ dst = (m==0)?uLa:(m==1)?vRa:(m==2)?vrxa:vlxa;
  #pragma unroll
  for (int nt=0;nt<6;nt++){
    int col = nt*16 + l16;
    if (col < 88){
      #pragma unroll
      for (int i=0;i<4;i++){
        int row = rows0 + quad*4 + i;
        dst[(size_t)row*88 + col] = acc[nt][i];
      }
    }
  }
}

// ---------------- Kernel 3: per-chunk state sums ----------------
__global__ __launch_bounds__(256) void k_chunksum(
    const float* __restrict__ gk, const float* __restrict__ gv,
    const float* __restrict__ uLa, const float* __restrict__ vRa,
    float* __restrict__ SL)
{
  const int bid = blockIdx.x;
  const int b = bid/NCH_, c = bid%NCH_;
  const size_t base64 = (size_t)(b*T_ + c*S_)*64;
  const size_t base88 = (size_t)(b*T_ + c*S_)*88;
  for (int p=0;p<4;p++){
    int e = threadIdx.x + p*256;
    if (e>=STATE_) break;
    float acc=0.f;
    if (e < 256){
      int n=e>>4;
      const float* A = gk + base64 + n*4 + ((e>>2)&3);
      const float* Bp = gv + base64 + n*4 + (e&3);
      for (int s=0;s<S_;s++) acc += A[s*64]*Bp[s*64];
    } else if (e < 832){
      int ia, ib; decodeWs(e, ia, ib);
      const float* A = uLa + base88 + ia;
      const float* Bp = vRa + base88 + ib;
      for (int s=0;s<S_;s++) acc += A[s*88]*Bp[s*88];
    } else {
      const float* A = gk + base64 + (e-832);
      for (int s=0;s<S_;s++) acc += A[s*64];
    }
    SL[(size_t)bid*STATE_ + e] = acc;
  }
}

// ---------------- Kernel 4: exclusive prefix over chunks — 4-way block split ------
__global__ __launch_bounds__(224) void k_prefix(const float* __restrict__ SL, float* __restrict__ SP){
  const int b = blockIdx.x;
  int e = blockIdx.y*224 + threadIdx.x;
  if (e >= STATE_) return;
  float run=0.f;
  for (int c=0;c<NCH_;c++){
    size_t idx = ((size_t)(b*NCH_+c))*STATE_ + e;
    SP[idx] = run; run += SL[idx];
  }
}

// ---------------- Kernel 5: parallel intra-chunk (S=16, 2 waves/block) ------------
// r6: LDS-issue-bound diagnosis -> halve S (total s-loop LDS instr halves);
// pad uvS stride 176->180 and ULs/URs L1-3 row stride 8->9 (kills the
// same-bank 8-way conflicts from pos*8 reads; SQ_LDS_BANK_CONFLICT was 3.5M).
__global__ __launch_bounds__(128) void k_intra(
    const float* __restrict__ gq, const float* __restrict__ gk, const float* __restrict__ gv,
    const float* __restrict__ uLa, const float* __restrict__ vRa,
    const float* __restrict__ vrxa, const float* __restrict__ vlxa,
    const float* __restrict__ SP,
    const void* __restrict__ UL0, const void* __restrict__ UL1, const void* __restrict__ UL2, const void* __restrict__ UL3,
    const void* __restrict__ UR0, const void* __restrict__ UR1, const void* __restrict__ UR2, const void* __restrict__ UR3,
    u16* __restrict__ Yb, const int* __restrict__ fl)
{
  __shared__ float kS[S_*64];
  __shared__ float vS[S_*64];
  __shared__ float uvS[S_*UVP];
  __shared__ float st0[STATE_];
  __shared__ float ULs[520], URs[520];   // L0@0(4x4), L1@16(8x9), L2@88(16x9), L3@232(32x9)
  const int f32 = fl[0];
  const int tid = threadIdx.x;
  const int bid = blockIdx.x;
  const int b = bid/NCH_, c = bid%NCH_;
  const int row0 = b*T_ + c*S_;

  const size_t r64 = (size_t)row0*64;
  for (int i=tid;i<S_*64;i+=128){ kS[i]=gk[r64+i]; vS[i]=gv[r64+i]; }
  const size_t r88 = (size_t)row0*88;
  for (int i=tid;i<S_*88;i+=128){
    int s=i/88, f=i-s*88;
    uvS[s*UVP+f]    = uLa[r88+i];
    uvS[s*UVP+88+f] = vRa[r88+i];
  }
  for (int e=tid;e<STATE_;e+=128) st0[e] = SP[(size_t)bid*STATE_+e];
  for (int e=tid;e<464;e+=128){
    int l, idx;
    if (e<16){ l=0; idx=e; } else if (e<80){ l=1; idx=e-16; }
    else if (e<208){ l=2; idx=e-80; } else { l=3; idx=e-208; }
    const void* ul = (l==0)?UL0:(l==1)?UL1:(l==2)?UL2:UL3;
    const void* ur = (l==0)?UR0:(l==1)?UR1:(l==2)?UR2:UR3;
    int dst = (l==0) ? e :
              (l==1) ? 16  + (idx>>3)*9 + (idx&7) :
              (l==2) ? 88  + (idx>>3)*9 + (idx&7) :
                       232 + (idx>>3)*9 + (idx&7);
    ULs[dst] = ldin(ul, idx, f32); URs[dst] = ldin(ur, idx, f32);
  }
  __syncthreads();

  const int w = tid>>6, lane = tid&63, tl = lane>>3, g = lane&7;
  const int t = w*8 + tl;
  const int n1 = g>>1, ri1 = (g&1)*4;
  const int n2 = g>>2, ri2 = (g&3)*2;
  const size_t row = (size_t)(row0 + t);

  float qr[8];
  { const float* qp = gq + row*64 + g*8;
    *(f32x4*)&qr[0] = *(const f32x4*)qp; *(f32x4*)&qr[4] = *(const f32x4*)(qp+4); }
  float rxL0[4], lxL0[4], rxL1[8], lxL1[8], rxL2[8], lxL2[8], rxL3[8], lxL3[8];
  { const float* rp = vrxa + row*88; const float* lp = vlxa + row*88;
    *(f32x4*)&rxL0[0] = *(const f32x4*)(rp + 4*g);
    *(f32x4*)&lxL0[0] = *(const f32x4*)(lp + 4*g);
    *(f32x4*)&rxL1[0] = *(const f32x4*)(rp + 32 + n1*8); *(f32x4*)&rxL1[4] = *(const f32x4*)(rp + 36 + n1*8);
    *(f32x4*)&lxL1[0] = *(const f32x4*)(lp + 32 + n1*8); *(f32x4*)&lxL1[4] = *(const f32x4*)(lp + 36 + n1*8);
    *(f32x4*)&rxL2[0] = *(const f32x4*)(rp + 64 + n2*8); *(f32x4*)&rxL2[4] = *(const f32x4*)(rp + 68 + n2*8);
    *(f32x4*)&lxL2[0] = *(const f32x4*)(lp + 64 + n2*8); *(f32x4*)&lxL2[4] = *(const f32x4*)(lp + 68 + n2*8);
    *(f32x4*)&rxL3[0] = *(const f32x4*)(rp + 80); *(f32x4*)&rxL3[4] = *(const f32x4*)(rp + 84);
    *(f32x4*)&lxL3[0] = *(const f32x4*)(lp + 80); *(f32x4*)&lxL3[4] = *(const f32x4*)(lp + 84); }

  float yacc[8], den = 0.f;
  #pragma unroll
  for (int cc=0;cc<8;cc++){
    int n = 2*g + (cc>>2);
    const float* m = &st0[n*16 + (cc&3)*4];
    const float* qp = &qr[(cc>>2)*4];
    yacc[cc] = m[0]*qp[0]+m[1]*qp[1]+m[2]*qp[2]+m[3]*qp[3];
    den += st0[832 + g*8 + cc]*qr[cc];
  }
  float gtL0[4], gbL0[4], gtL1[4], gbL1[4], gtL2[2], gbL2[2], gtL3, gbL3;
  #pragma unroll
  for (int cc=0;cc<4;cc++){
    const float* m = &st0[256 + g*16 + cc*4];
    gtL0[cc] = m[0]*rxL0[0]+m[1]*rxL0[1]+m[2]*rxL0[2]+m[3]*rxL0[3];
    float s2 = 0.f;
    #pragma unroll
    for (int j=0;j<4;j++) s2 += st0[256 + g*16 + j*4 + cc]*lxL0[j];
    gbL0[cc] = s2;
  }
  #pragma unroll
  for (int cc=0;cc<4;cc++){
    int ri = ri1 + cc;
    float s1=0.f, s2=0.f;
    #pragma unroll
    for (int j=0;j<8;j++){
      s1 += st0[384 + n1*64 + ri*8 + j]*rxL1[j];
      s2 += st0[384 + n1*64 + j*8 + ri]*lxL1[j];
    }
    gtL1[cc]=s1; gbL1[cc]=s2;
  }
  #pragma unroll
  for (int cc=0;cc<2;cc++){
    int ri = ri2 + cc;
    float s1=0.f, s2=0.f;
    #pragma unroll
    for (int j=0;j<8;j++){
      s1 += st0[640 + n2*64 + ri*8 + j]*rxL2[j];
      s2 += st0[640 + n2*64 + j*8 + ri]*lxL2[j];
    }
    gtL2[cc]=s1; gbL2[cc]=s2;
  }
  { float s1=0.f, s2=0.f;
    #pragma unroll
    for (int j=0;j<8;j++){
      s1 += st0[768 + g*8 + j]*rxL3[j];
      s2 += st0[768 + j*8 + g]*lxL3[j];
    }
    gtL3=s1; gbL3=s2; }

  const int smax = w*8 + 8;
  for (int s=0; s<smax; s++){
    const float* ks_ = &kS[s*64 + g*8];
    const float* vs_ = &vS[s*64 + g*8];
    const float* uL_ = &uvS[s*UVP];
    const float* vR_ = &uvS[s*UVP + 88];
    float dv0 = vs_[0]*qr[0]+vs_[1]*qr[1]+vs_[2]*qr[2]+vs_[3]*qr[3];
    float dv1 = vs_[4]*qr[4]+vs_[5]*qr[5]+vs_[6]*qr[6]+vs_[7]*qr[7];
    float dn = 0.f;
    #pragma unroll
    for (int cc=0;cc<8;cc++) dn += ks_[cc]*qr[cc];
    float d1L0=0.f,d2L0=0.f;
    #pragma unroll
    for (int j=0;j<4;j++){ d1L0 += vR_[4*g+j]*rxL0[j]; d2L0 += uL_[4*g+j]*lxL0[j]; }
    float d1L1=0.f,d2L1=0.f;
    #pragma unroll
    for (int j=0;j<8;j++){ d1L1 += vR_[32+n1*8+j]*rxL1[j]; d2L1 += uL_[32+n1*8+j]*lxL1[j]; }
    float d1L2=0.f,d2L2=0.f;
    #pragma unroll
    for (int j=0;j<8;j++){ d1L2 += vR_[64+n2*8+j]*rxL2[j]; d2L2 += uL_[64+n2*8+j]*lxL2[j]; }
    float d1L3=0.f,d2L3=0.f;
    #pragma unroll
    for (int j=0;j<8;j++){ d1L3 += vR_[80+j]*rxL3[j]; d2L3 += uL_[80+j]*lxL3[j]; }
    if (s<=t){
      den += dn;
      #pragma unroll
      for (int cc=0;cc<8;cc++) yacc[cc] += ks_[cc]*((cc<4)?dv0:dv1);
      #pragma unroll
      for (int cc=0;cc<4;cc++){
        gtL0[cc] += uL_[4*g+cc]*d1L0;          gbL0[cc] += vR_[4*g+cc]*d2L0;
        gtL1[cc] += uL_[32+n1*8+ri1+cc]*d1L1;  gbL1[cc] += vR_[32+n1*8+ri1+cc]*d2L1;
      }
      #pragma unroll
      for (int cc=0;cc<2;cc++){
        gtL2[cc] += uL_[64+n2*8+ri2+cc]*d1L2;  gbL2[cc] += vR_[64+n2*8+ri2+cc]*d2L2;
      }
      gtL3 += uL_[80+g]*d1L3;  gbL3 += vR_[80+g]*d2L3;
    }
  }
  __syncthreads();

  { float* gr = &uvS[t*UVP];
    #pragma unroll
    for (int cc=0;cc<4;cc++){
      gr[4*g+cc] = gtL0[cc];                 gr[88+4*g+cc] = gbL0[cc];
      gr[32+n1*8+ri1+cc] = gtL1[cc];         gr[88+32+n1*8+ri1+cc] = gbL1[cc];
    }
    #pragma unroll
    for (int cc=0;cc<2;cc++){
      gr[64+n2*8+ri2+cc] = gtL2[cc];         gr[88+64+n2*8+ri2+cc] = gbL2[cc];
    }
    gr[80+g] = gtL3;  gr[88+80+g] = gbL3;
  }
  __syncthreads();

  den += __shfl_xor(den,1); den += __shfl_xor(den,2); den += __shfl_xor(den,4);
  float inv = 1.f / fmaxf(den, 1e-6f);
  const float* gr = &uvS[t*UVP];
  float yout[8];
  #pragma unroll
  for (int cc=0;cc<8;cc++){
    int j = g*8 + cc;
    float y = yacc[cc];
    if (cc<4){
      #pragma unroll
      for (int rr=0;rr<4;rr++) y += ULs[cc*4+rr]*gr[g*4+rr];
    } else {
      #pragma unroll
      for (int rr=0;rr<4;rr++) y += URs[(cc-4)*4+rr]*gr[88+g*4+rr];
    }
    { int seg=j>>4, pos=j&15;
      if (pos<8){
        #pragma unroll
        for (int rr=0;rr<8;rr++) y += ULs[16+pos*9+rr]*gr[32+seg*8+rr];
      } else {
        #pragma unroll
        for (int rr=0;rr<8;rr++) y += URs[16+(pos-8)*9+rr]*gr[88+32+seg*8+rr];
      } }
    { int seg=j>>5, pos=j&31;
      if (pos<16){
        #pragma unroll
        for (int rr=0;rr<8;rr++) y += ULs[88+pos*9+rr]*gr[64+seg*8+rr];
      } else {
        #pragma unroll
        for (int rr=0;rr<8;rr++) y += URs[88+(pos-16)*9+rr]*gr[88+64+seg*8+rr];
      } }
    { int pos=j;
      if (pos<32){
        #pragma unroll
        for (int rr=0;rr<8;rr++) y += ULs[232+pos*9+rr]*gr[80+rr];
      } else {
        #pragma unroll
        for (int rr=0;rr<8;rr++) y += URs[232+(pos-32)*9+rr]*gr[88+80+rr];
      } }
    yout[cc] = y*inv;
  }
  u16* yp = Yb + row*64 + g*8;
  ushort4 o1, o2;
  o1.x=f2b(yout[0]); o1.y=f2b(yout[1]); o1.z=f2b(yout[2]); o1.w=f2b(yout[3]);
  o2.x=f2b(yout[4]); o2.y=f2b(yout[5]); o2.z=f2b(yout[6]); o2.w=f2b(yout[7]);
  *(ushort4*)yp = o1;
  *(ushort4*)(yp+4) = o2;
}

// ---------------- Kernel 6: output projection — 8-way col split ----------------
__global__ __launch_bounds__(64,4) void k_outproj3(
    const u16* __restrict__ Yb, const u16* __restrict__ WoF, void* __restrict__ outv,
    const int* __restrict__ fl)
{
  const int f32 = fl[0];
  const int rows0 = blockIdx.x*32;
  const int nt0 = blockIdx.y*8;
  const int lane = threadIdx.x;
  const int quad = lane>>4, l16 = lane&15;

  f32x4 acc[16];
  #pragma unroll
  for (int i=0;i<16;i++) acc[i] = (f32x4){0.f,0.f,0.f,0.f};

  #pragma unroll
  for (int ks=0;ks<2;ks++){
    int ko = ks*32 + quad*8;
    bf16x8 a0 = *(const bf16x8*)(Yb + (size_t)(rows0 + l16)*DH_ + ko);
    bf16x8 a1 = *(const bf16x8*)(Yb + (size_t)(rows0 + 16 + l16)*DH_ + ko);
    #pragma unroll
    for (int nt=0;nt<8;nt++){
      bf16x8 b = *(const bf16x8*)(WoF + ((size_t)(ks*64 + nt0 + nt)*64 + lane)*8);
      acc[nt]   = __builtin_amdgcn_mfma_f32_16x16x32_bf16(a0,b,acc[nt],0,0,0);
      acc[8+nt] = __builtin_amdgcn_mfma_f32_16x16x32_bf16(a1,b,acc[8+nt],0,0,0);
    }
  }
  #pragma unroll
  for (int sp=0;sp<2;sp++){
    #pragma unroll
    for (int nt=0;nt<8;nt++){
      #pragma unroll
      for (int i=0;i<4;i++){
        int row = rows0 + sp*16 + quad*4 + i;
        int col = (nt0+nt)*16 + l16;
        size_t idx = (size_t)row*DM_ + col;
        float v = acc[sp*8+nt][i];
        if (f32) ((float*)outv)[idx] = v;
        else ((u16*)outv)[idx] = f2b(v);
      }
    }
  }
}

extern "C" void kernel_launch(void* const* d_in, const int* in_sizes, int n_in,
                              void* d_out, int out_size, void* d_ws, size_t ws_size,
                              hipStream_t stream) {
  const void* x  = d_in[0];
  const void* Wq = d_in[1];
  const void* Wk = d_in[2];
  const void* Wv = d_in[3];
  const void* Wo = d_in[4];
  const void* UL[4] = {d_in[5],d_in[6],d_in[7],d_in[8]};
  const void* VR[4] = {d_in[9],d_in[10],d_in[11],d_in[12]};
  const void* UR[4] = {d_in[13],d_in[14],d_in[15],d_in[16]};
  const void* VL[4] = {d_in[17],d_in[18],d_in[19],d_in[20]};

  int* flag = (int*)d_ws;
  float* ws = (float*)d_ws + 16;
  float* q    = ws;
  float* kf   = q    + (size_t)BT_*64;
  float* vf   = kf   + (size_t)BT_*64;
  float* uLa  = vf   + (size_t)BT_*64;
  float* vRa  = uLa  + (size_t)BT_*88;
  float* vrxa = vRa  + (size_t)BT_*88;
  float* vlxa = vrxa + (size_t)BT_*88;
  float* SL   = vlxa + (size_t)BT_*88;
  float* SP   = SL   + (size_t)B_*NCH_*STATE_;
  u16*   Yb   = (u16*)(SP + (size_t)B_*NCH_*STATE_);
  u16*   WF   = Yb  + (size_t)BT_*64;
  u16*   WoF  = WF  + (size_t)196608;
  u16*   PF   = WoF + (size_t)65536;
  u16*   qb16 = PF  + (size_t)18432;
  u16*   kb16 = qb16 + (size_t)BT_*64;
  u16*   vb16 = kb16 + (size_t)BT_*64;

  k_detect<<<1, 64, 0, stream>>>((const u16*)x, flag);
  k_wfrag<<<137, 256, 0, stream>>>(Wq, Wk, Wv, Wo,
      UL[0],UL[1],UL[2],UL[3], VR[0],VR[1],VR[2],VR[3], VL[0],VL[1],VL[2],VL[3],
      WF, WoF, PF, flag);
  k_proj7<<<BT_/64, 512, 0, stream>>>(x, WF, q, kf, vf, qb16, kb16, vb16, flag);
  k_prep3<<<dim3(BT_/16, 4), 64, 0, stream>>>(qb16, kb16, vb16, PF, uLa, vRa, vrxa, vlxa);
  k_chunksum<<<B_*NCH_, 256, 0, stream>>>(kf, vf, uLa, vRa, SL);
  k_prefix<<<dim3(B_, 4), 224, 0, stream>>>(SL, SP);
  k_intra<<<B_*NCH_, 128, 0, stream>>>(q, kf, vf, uLa, vRa, vrxa, vlxa, SP,
      UL[0],UL[1],UL[2],UL[3], UR[0],UR[1],UR[2],UR[3], Yb, flag);
  k_outproj3<<<dim3(512, 8), 64, 0, stream>>>(Yb, WoF, d_out, flag);
}

// Round 7
// 241.863 us; speedup vs baseline: 1.1547x; 1.0019x over previous
//
#include <hip/hip_runtime.h>
#include <hip/hip_bf16.h>

typedef unsigned short u16;
typedef __attribute__((ext_vector_type(8))) short bf16x8;
typedef __attribute__((ext_vector_type(4))) float f32x4;

#define B_ 8
#define T_ 2048
#define BT_ (B_*T_)
#define DM_ 1024
#define DH_ 64
#define NCH_ 128           // chunks per batch
#define S_ (T_/NCH_)       // 16 steps per chunk
#define STATE_ 896         // leaf 256 + Ws 576 + z 64
#define UVP 180            // padded uvS row stride

__device__ __forceinline__ float b2f(u16 u){ unsigned v=((unsigned)u)<<16; float f; __builtin_memcpy(&f,&v,4); return f; }
__device__ __forceinline__ u16 f2b(float f){ __hip_bfloat16 h=__float2bfloat16(f); u16 u; __builtin_memcpy(&u,&h,2); return u; }

__device__ __forceinline__ float ldin(const void* p, size_t i, int f32){
  return f32 ? ((const float*)p)[i] : b2f(((const u16*)p)[i]);
}
// load 8 consecutive elements as bf16x8 (converting from fp32 if needed)
__device__ __forceinline__ bf16x8 ld8bf(const void* p, size_t i, int f32){
  if (f32){
    f32x4 v0 = *(const f32x4*)((const float*)p + i);
    f32x4 v1 = *(const f32x4*)((const float*)p + i + 4);
    bf16x8 r;
    #pragma unroll
    for (int j=0;j<4;j++){ r[j] = (short)f2b(v0[j]); r[4+j] = (short)f2b(v1[j]); }
    return r;
  }
  return *(const bf16x8*)((const u16*)p + i);
}

// async global->LDS, 16B per lane
__device__ __forceinline__ void gl_lds16(const void* g, void* l){
  __builtin_amdgcn_global_load_lds((const __attribute__((address_space(1))) unsigned int*)g,
                                   (__attribute__((address_space(3))) unsigned int*)l, 16, 0, 0);
}

// state layout: leaf [0,256): n*16+i*4+j ; Ws: L0@256, L1@384, L2@640, L3@768 ; z@832
__device__ __forceinline__ void decodeWs(int e, int& ia, int& ib){
  if (e<384){ int o=e-256, n=o>>4; ia=n*4+((o>>2)&3); ib=n*4+(o&3); }
  else if (e<640){ int o=e-384, n=o>>6; ia=32+n*8+((o>>3)&7); ib=32+n*8+(o&7); }
  else if (e<768){ int o=e-640, n=o>>6; ia=64+n*8+((o>>3)&7); ib=64+n*8+(o&7); }
  else { int o=e-768; ia=80+((o>>3)&7); ib=80+(o&7); }
}
__device__ __forceinline__ void decode88(int f, int& l, int& n, int& ri){
  if (f<32){ l=0; n=f>>2; ri=f&3; }
  else if (f<64){ l=1; n=(f-32)>>3; ri=f&7; }
  else if (f<80){ l=2; n=(f-64)>>3; ri=f&7; }
  else { l=3; n=0; ri=f&7; }
}

// ---------------- Kernel 0: dtype detection ----------------
__global__ __launch_bounds__(64) void k_detect(const u16* __restrict__ x, int* __restrict__ flag){
  int tid = threadIdx.x;
  int sane = 0;
  for (int i = tid; i < 4096; i += 64){
    u16 u = x[i];
    int e = (u >> 7) & 0xFF;
    if ((u & 0x7FFF) == 0 || (e >= 100 && e <= 140)) sane++;
  }
  #pragma unroll
  for (int o = 32; o > 0; o >>= 1) sane += __shfl_down(sane, o);
  if (tid == 0) flag[0] = (sane < 3600) ? 1 : 0;
}

// ---------------- Kernel 0c: weight/basis -> MFMA B-fragment layout (bf16) ------
__global__ __launch_bounds__(256) void k_wfrag(
    const void* __restrict__ Wq, const void* __restrict__ Wk, const void* __restrict__ Wv,
    const void* __restrict__ Wo,
    const void* __restrict__ UL0, const void* __restrict__ UL1, const void* __restrict__ UL2, const void* __restrict__ UL3,
    const void* __restrict__ VR0, const void* __restrict__ VR1, const void* __restrict__ VR2, const void* __restrict__ VR3,
    const void* __restrict__ VL0, const void* __restrict__ VL1, const void* __restrict__ VL2, const void* __restrict__ VL3,
    u16* __restrict__ WF, u16* __restrict__ WoF, u16* __restrict__ PF,
    const int* __restrict__ fl)
{
  const int f32 = fl[0];
  int e = blockIdx.x*256 + threadIdx.x;
  if (e < 24576){
    int m = e >> 13;
    int rem = e & 8191;
    int ks = rem >> 8;
    int nt = (rem >> 6) & 3;
    int lane = rem & 63;
    const void* W = (m==0)?Wq:((m==1)?Wk:Wv);
    int kr = ks*32 + (lane>>4)*8;
    int col = nt*16 + (lane&15);
    u16 o[8];
    #pragma unroll
    for (int j=0;j<8;j++) o[j] = f2b(ldin(W, (size_t)(kr+j)*DH_ + col, f32));
    u16* dst = WF + (size_t)e*8;
    #pragma unroll
    for (int j=0;j<8;j++) dst[j] = o[j];
  } else if (e < 32768){
    int eo = e - 24576;
    int ks = eo >> 12;
    int nt = (eo >> 6) & 63;
    int lane = eo & 63;
    int kr = ks*32 + (lane>>4)*8;
    int col = nt*16 + (lane&15);
    u16 o[8];
    #pragma unroll
    for (int j=0;j<8;j++) o[j] = f2b(ldin(Wo, (size_t)(kr+j)*DM_ + col, f32));
    u16* dst = WoF + (size_t)eo*8;
    #pragma unroll
    for (int j=0;j<8;j++) dst[j] = o[j];
  } else if (e < 35072){
    int pe = e - 32768;         // 0..2303
    int lane = pe & 63;
    int nt = (pe >> 6) % 6;
    int mk = pe / 384;          // mat*2+ks
    int ks = mk & 1, mat = mk >> 1;
    int col = nt*16 + (lane&15);
    int dbase = ks*32 + (lane>>4)*8;
    const int BSl[4]={4,8,16,32}; const int Rl[4]={4,8,8,8};
    u16 o[8];
    #pragma unroll
    for (int j=0;j<8;j++){
      float val = 0.f;
      if (col < 88){
        int l,n,ri; decode88(col,l,n,ri);
        int bs=BSl[l], r=Rl[l];
        int lo = n*2*bs + ((mat==1)?bs:0);
        int d = dbase + j;
        if (d >= lo && d < lo+bs){
          const void* Up;
          if (mat==0)      Up = (l==0)?UL0:(l==1)?UL1:(l==2)?UL2:UL3;
          else if (mat==1) Up = (l==0)?VR0:(l==1)?VR1:(l==2)?VR2:VR3;
          else             Up = (l==0)?VL0:(l==1)?VL1:(l==2)?VL2:VL3;
          val = ldin(Up, (size_t)(d-lo)*r + ri, f32);
        }
      }
      o[j] = f2b(val);
    }
    u16* dst = PF + (size_t)pe*8;
    #pragma unroll
    for (int j=0;j<8;j++) dst[j] = o[j];
  }
}

// ---------------- Kernel 1: QKV projection — counted-vmcnt 3-buffer pipeline ------
// r7: per-step vmcnt(0)+barrier drained each STAGE in the same step it was issued
// (latency exposed 16x). Now: A-frags all preloaded to regs (no consumer loads in
// loop -> no compiler auto-vmcnt); 3 x 24 KB LDS buffers; STAGE(t+2) issued at end
// of step t, consumed 2 steps later; wait vmcnt(3) keeps S(t+1) in flight (T4).
// Raw s_barrier + sched_barrier(0) per rule #18. Grid 256 = 1 block/CU.
__global__ __launch_bounds__(512, 1) void k_proj8(
    const void* __restrict__ x, const u16* __restrict__ WF,
    float* __restrict__ oq, float* __restrict__ ok_, float* __restrict__ ov,
    u16* __restrict__ qb16, u16* __restrict__ kb16, u16* __restrict__ vb16,
    const int* __restrict__ fl)
{
  __shared__ __align__(16) char sh[73728];   // 3 x 24 KB stage; first 48 KB reused for reduction
  const int f32 = fl[0];
  const int tid = threadIdx.x;
  const int wv = tid>>6;          // 0..7
  const int mg = wv>>1;           // row group 0..3 (16 rows each)
  const int h  = wv&1;            // K half (16 ks-steps each)
  const int lane = tid&63;
  const int quad = lane>>4, l16 = lane&15;
  const int rows0 = blockIdx.x*64 + mg*16;
  const size_t rowA = (size_t)(rows0 + l16)*DM_;

  f32x4 acc[12];
  #pragma unroll
  for (int i=0;i<12;i++) acc[i] = (f32x4){0.f,0.f,0.f,0.f};

  // stage the 24 fragments (12 per K-half) of step t into buffer buf (3 gl_lds/thread)
  #define STAGE(t, buf) do{                                                   \
    _Pragma("unroll")                                                         \
    for (int r=0;r<3;r++){                                                    \
      int s = wv + r*8;                                                       \
      int hs = (s>=12) ? 1 : 0;                                               \
      int f = s - hs*12;                                                      \
      int m_ = f>>2, nt_ = f&3;                                               \
      int ks_ = hs*16 + (t);                                                  \
      const char* src = (const char*)WF + (size_t)((m_*32+ks_)*4+nt_)*1024 + (size_t)lane*16; \
      char* dst = sh + (buf)*24576 + hs*12288 + f*1024 + lane*16;             \
      gl_lds16(src, dst);                                                     \
    } }while(0)

  // prologue: all 16 A-fragments to registers, then 2 stages in flight
  bf16x8 a[16];
  #pragma unroll
  for (int t=0;t<16;t++) a[t] = ld8bf(x, rowA + (size_t)(h*16+t)*32 + quad*8, f32);
  STAGE(0, 0);
  STAGE(1, 1);
  __builtin_amdgcn_sched_barrier(0);

  #pragma unroll
  for (int t=0;t<16;t++){
    if (t<15) asm volatile("s_waitcnt vmcnt(3)" ::: "memory");   // S(t) landed, S(t+1) in flight
    else      asm volatile("s_waitcnt vmcnt(0)" ::: "memory");
    __builtin_amdgcn_s_barrier();
    __builtin_amdgcn_sched_barrier(0);
    const char* bb = sh + (t%3)*24576 + h*12288;
    #pragma unroll
    for (int f=0;f<12;f++){
      bf16x8 b = *(const bf16x8*)(bb + f*1024 + lane*16);
      acc[f] = __builtin_amdgcn_mfma_f32_16x16x32_bf16(a[t], b, acc[f],0,0,0);
    }
    if (t<14) STAGE(t+2, (t+2)%3);   // into buffer freed at step t-1's barrier
    __builtin_amdgcn_sched_barrier(0);
  }
  #undef STAGE
  __syncthreads();   // full drain before reduction aliasing

  // cross-K-half reduction through LDS (stage buffers are dead now)
  if (h==1){
    #pragma unroll
    for (int i=0;i<12;i++) ((f32x4*)sh)[(mg*12+i)*64 + lane] = acc[i];
  }
  __syncthreads();
  if (h==0){
    #pragma unroll
    for (int i=0;i<12;i++){
      f32x4 r = ((f32x4*)sh)[(mg*12+i)*64 + lane];
      acc[i][0]+=r[0]; acc[i][1]+=r[1]; acc[i][2]+=r[2]; acc[i][3]+=r[3];
    }
    #pragma unroll
    for (int m=0;m<3;m++){
      float* __restrict__ outp = (m==0)?oq:((m==1)?ok_:ov);
      u16* __restrict__ outb = (m==0)?qb16:((m==1)?kb16:vb16);
      #pragma unroll
      for (int nt=0;nt<4;nt++){
        #pragma unroll
        for (int i=0;i<4;i++){
          int row = rows0 + quad*4 + i;
          int col = nt*16 + l16;
          float val = acc[m*4+nt][i];
          if (m<2) val = (val>0.f)? (val+1.f) : expf(val);  // elu1
          outp[(size_t)row*DH_ + col] = val;
          outb[(size_t)row*DH_ + col] = f2b(val);
        }
      }
    }
  }
}

// ---------------- Kernel 2: basis projections via MFMA — per-matrix split --------
__global__ __launch_bounds__(64) void k_prep3(
    const u16* __restrict__ qb16, const u16* __restrict__ kb16, const u16* __restrict__ vb16,
    const u16* __restrict__ PF,
    float* __restrict__ uLa, float* __restrict__ vRa, float* __restrict__ vrxa, float* __restrict__ vlxa)
{
  const int m = blockIdx.y;          // 0:uL=K@Mu 1:vR=V@Mv 2:vrx=Q@Mv 3:vlx=Q@Mlx
  const int rows0 = blockIdx.x*16;
  const int lane = threadIdx.x;
  const int quad = lane>>4, l16 = lane&15;

  const u16* __restrict__ src = (m==0)?kb16:((m==1)?vb16:qb16);
  const int mat = (m==0)?0:((m==3)?2:1);   // PF matrix index {Mu,Mv,Mlx}

  bf16x8 a[2];
  #pragma unroll
  for (int ks=0;ks<2;ks++){
    size_t off = (size_t)(rows0 + l16)*DH_ + ks*32 + quad*8;
    a[ks] = *(const bf16x8*)(src + off);
  }
  f32x4 acc[6];
  #pragma unroll
  for (int nt=0;nt<6;nt++) acc[nt] = (f32x4){0.f,0.f,0.f,0.f};

  #pragma unroll
  for (int ks=0;ks<2;ks++){
    #pragma unroll
    for (int nt=0;nt<6;nt++){
      bf16x8 b = *(const bf16x8*)(PF + ((size_t)((mat*2+ks)*6+nt)*64 + lane)*8);
      acc[nt] = __builtin_amdgcn_mfma_f32_16x16x32_bf16(a[ks], b, acc[nt],0,0,0);
    }
  }
  float* __restrict__ dst = (m==0)?uLa:(m==1)?vRa:(m==2)?vrxa:vlxa;
  #pragma unroll
  for (int nt=0;nt<6;nt++){
    int col = nt*16 + l16;
    if (col < 88){
      #pragma unroll
      for (int i=0;i<4;i++){
        int row = rows0 + quad*4 + i;
        dst[(size_t)row*88 + col] = acc[nt][i];
      }
    }
  }
}

// ---------------- Kernel 3: per-chunk state sums ----------------
__global__ __launch_bounds__(256) void k_chunksum(
    const float* __restrict__ gk, const float* __restrict__ gv,
    const float* __restrict__ uLa, const float* __restrict__ vRa,
    float* __restrict__ SL)
{
  const int bid = blockIdx.x;
  const int b = bid/NCH_, c = bid%NCH_;
  const size_t base64 = (size_t)(b*T_ + c*S_)*64;
  const size_t base88 = (size_t)(b*T_ + c*S_)*88;
  for (int p=0;p<4;p++){
    int e = threadIdx.x + p*256;
    if (e>=STATE_) break;
    float acc=0.f;
    if (e < 256){
      int n=e>>4;
      const float* A = gk + base64 + n*4 + ((e>>2)&3);
      const float* Bp = gv + base64 + n*4 + (e&3);
      for (int s=0;s<S_;s++) acc += A[s*64]*Bp[s*64];
    } else if (e < 832){
      int ia, ib; decodeWs(e, ia, ib);
      const float* A = uLa + base88 + ia;
      const float* Bp = vRa + base88 + ib;
      for (int s=0;s<S_;s++) acc += A[s*88]*Bp[s*88];
    } else {
      const float* A = gk + base64 + (e-832);
      for (int s=0;s<S_;s++) acc += A[s*64];
    }
    SL[(size_t)bid*STATE_ + e] = acc;
  }
}

// ---------------- Kernel 4: exclusive prefix over chunks — 4-way block split ------
__global__ __launch_bounds__(224) void k_prefix(const float* __restrict__ SL, float* __restrict__ SP){
  const int b = blockIdx.x;
  int e = blockIdx.y*224 + threadIdx.x;
  if (e >= STATE_) return;
  float run=0.f;
  for (int c=0;c<NCH_;c++){
    size_t idx = ((size_t)(b*NCH_+c))*STATE_ + e;
    SP[idx] = run; run += SL[idx];
  }
}

// ---------------- Kernel 5: parallel intra-chunk (S=16, 2 waves/block) ------------
__global__ __launch_bounds__(128) void k_intra(
    const float* __restrict__ gq, const float* __restrict__ gk, const float* __restrict__ gv,
    const float* __restrict__ uLa, const float* __restrict__ vRa,
    const float* __restrict__ vrxa, const float* __restrict__ vlxa,
    const float* __restrict__ SP,
    const void* __restrict__ UL0, const void* __restrict__ UL1, const void* __restrict__ UL2, const void* __restrict__ UL3,
    const void* __restrict__ UR0, const void* __restrict__ UR1, const void* __restrict__ UR2, const void* __restrict__ UR3,
    u16* __restrict__ Yb, const int* __restrict__ fl)
{
  __shared__ float kS[S_*64];
  __shared__ float vS[S_*64];
  __shared__ float uvS[S_*UVP];
  __shared__ float st0[STATE_];
  __shared__ float ULs[520], URs[520];   // L0@0(4x4), L1@16(8x9), L2@88(16x9), L3@232(32x9)
  const int f32 = fl[0];
  const int tid = threadIdx.x;
  const int bid = blockIdx.x;
  const int b = bid/NCH_, c = bid%NCH_;
  const int row0 = b*T_ + c*S_;

  const size_t r64 = (size_t)row0*64;
  for (int i=tid;i<S_*64;i+=128){ kS[i]=gk[r64+i]; vS[i]=gv[r64+i]; }
  const size_t r88 = (size_t)row0*88;
  for (int i=tid;i<S_*88;i+=128){
    int s=i/88, f=i-s*88;
    uvS[s*UVP+f]    = uLa[r88+i];
    uvS[s*UVP+88+f] = vRa[r88+i];
  }
  for (int e=tid;e<STATE_;e+=128) st0[e] = SP[(size_t)bid*STATE_+e];
  for (int e=tid;e<464;e+=128){
    int l, idx;
    if (e<16){ l=0; idx=e; } else if (e<80){ l=1; idx=e-16; }
    else if (e<208){ l=2; idx=e-80; } else { l=3; idx=e-208; }
    const void* ul = (l==0)?UL0:(l==1)?UL1:(l==2)?UL2:UL3;
    const void* ur = (l==0)?UR0:(l==1)?UR1:(l==2)?UR2:UR3;
    int dst = (l==0) ? e :
              (l==1) ? 16  + (idx>>3)*9 + (idx&7) :
              (l==2) ? 88  + (idx>>3)*9 + (idx&7) :
                       232 + (idx>>3)*9 + (idx&7);
    ULs[dst] = ldin(ul, idx, f32); URs[dst] = ldin(ur, idx, f32);
  }
  __syncthreads();

  const int w = tid>>6, lane = tid&63, tl = lane>>3, g = lane&7;
  const int t = w*8 + tl;
  const int n1 = g>>1, ri1 = (g&1)*4;
  const int n2 = g>>2, ri2 = (g&3)*2;
  const size_t row = (size_t)(row0 + t);

  float qr[8];
  { const float* qp = gq + row*64 + g*8;
    *(f32x4*)&qr[0] = *(const f32x4*)qp; *(f32x4*)&qr[4] = *(const f32x4*)(qp+4); }
  float rxL0[4], lxL0[4], rxL1[8], lxL1[8], rxL2[8], lxL2[8], rxL3[8], lxL3[8];
  { const float* rp = vrxa + row*88; const float* lp = vlxa + row*88;
    *(f32x4*)&rxL0[0] = *(const f32x4*)(rp + 4*g);
    *(f32x4*)&lxL0[0] = *(const f32x4*)(lp + 4*g);
    *(f32x4*)&rxL1[0] = *(const f32x4*)(rp + 32 + n1*8); *(f32x4*)&rxL1[4] = *(const f32x4*)(rp + 36 + n1*8);
    *(f32x4*)&lxL1[0] = *(const f32x4*)(lp + 32 + n1*8); *(f32x4*)&lxL1[4] = *(const f32x4*)(lp + 36 + n1*8);
    *(f32x4*)&rxL2[0] = *(const f32x4*)(rp + 64 + n2*8); *(f32x4*)&rxL2[4] = *(const f32x4*)(rp + 68 + n2*8);
    *(f32x4*)&lxL2[0] = *(const f32x4*)(lp + 64 + n2*8); *(f32x4*)&lxL2[4] = *(const f32x4*)(lp + 68 + n2*8);
    *(f32x4*)&rxL3[0] = *(const f32x4*)(rp + 80); *(f32x4*)&rxL3[4] = *(const f32x4*)(rp + 84);
    *(f32x4*)&lxL3[0] = *(const f32x4*)(lp + 80); *(f32x4*)&lxL3[4] = *(const f32x4*)(lp + 84); }

  float yacc[8], den = 0.f;
  #pragma unroll
  for (int cc=0;cc<8;cc++){
    int n = 2*g + (cc>>2);
    const float* m = &st0[n*16 + (cc&3)*4];
    const float* qp = &qr[(cc>>2)*4];
    yacc[cc] = m[0]*qp[0]+m[1]*qp[1]+m[2]*qp[2]+m[3]*qp[3];
    den += st0[832 + g*8 + cc]*qr[cc];
  }
  float gtL0[4], gbL0[4], gtL1[4], gbL1[4], gtL2[2], gbL2[2], gtL3, gbL3;
  #pragma unroll
  for (int cc=0;cc<4;cc++){
    const float* m = &st0[256 + g*16 + cc*4];
    gtL0[cc] = m[0]*rxL0[0]+m[1]*rxL0[1]+m[2]*rxL0[2]+m[3]*rxL0[3];
    float s2 = 0.f;
    #pragma unroll
    for (int j=0;j<4;j++) s2 += st0[256 + g*16 + j*4 + cc]*lxL0[j];
    gbL0[cc] = s2;
  }
  #pragma unroll
  for (int cc=0;cc<4;cc++){
    int ri = ri1 + cc;
    float s1=0.f, s2=0.f;
    #pragma unroll
    for (int j=0;j<8;j++){
      s1 += st0[384 + n1*64 + ri*8 + j]*rxL1[j];
      s2 += st0[384 + n1*64 + j*8 + ri]*lxL1[j];
    }
    gtL1[cc]=s1; gbL1[cc]=s2;
  }
  #pragma unroll
  for (int cc=0;cc<2;cc++){
    int ri = ri2 + cc;
    float s1=0.f, s2=0.f;
    #pragma unroll
    for (int j=0;j<8;j++){
      s1 += st0[640 + n2*64 + ri*8 + j]*rxL2[j];
      s2 += st0[640 + n2*64 + j*8 + ri]*lxL2[j];
    }
    gtL2[cc]=s1; gbL2[cc]=s2;
  }
  { float s1=0.f, s2=0.f;
    #pragma unroll
    for (int j=0;j<8;j++){
      s1 += st0[768 + g*8 + j]*rxL3[j];
      s2 += st0[768 + j*8 + g]*lxL3[j];
    }
    gtL3=s1; gbL3=s2; }

  const int smax = w*8 + 8;
  for (int s=0; s<smax; s++){
    const float* ks_ = &kS[s*64 + g*8];
    const float* vs_ = &vS[s*64 + g*8];
    const float* uL_ = &uvS[s*UVP];
    const float* vR_ = &uvS[s*UVP + 88];
    float dv0 = vs_[0]*qr[0]+vs_[1]*qr[1]+vs_[2]*qr[2]+vs_[3]*qr[3];
    float dv1 = vs_[4]*qr[4]+vs_[5]*qr[5]+vs_[6]*qr[6]+vs_[7]*qr[7];
    float dn = 0.f;
    #pragma unroll
    for (int cc=0;cc<8;cc++) dn += ks_[cc]*qr[cc];
    float d1L0=0.f,d2L0=0.f;
    #pragma unroll
    for (int j=0;j<4;j++){ d1L0 += vR_[4*g+j]*rxL0[j]; d2L0 += uL_[4*g+j]*lxL0[j]; }
    float d1L1=0.f,d2L1=0.f;
    #pragma unroll
    for (int j=0;j<8;j++){ d1L1 += vR_[32+n1*8+j]*rxL1[j]; d2L1 += uL_[32+n1*8+j]*lxL1[j]; }
    float d1L2=0.f,d2L2=0.f;
    #pragma unroll
    for (int j=0;j<8;j++){ d1L2 += vR_[64+n2*8+j]*rxL2[j]; d2L2 += uL_[64+n2*8+j]*lxL2[j]; }
    float d1L3=0.f,d2L3=0.f;
    #pragma unroll
    for (int j=0;j<8;j++){ d1L3 += vR_[80+j]*rxL3[j]; d2L3 += uL_[80+j]*lxL3[j]; }
    if (s<=t){
      den += dn;
      #pragma unroll
      for (int cc=0;cc<8;cc++) yacc[cc] += ks_[cc]*((cc<4)?dv0:dv1);
      #pragma unroll
      for (int cc=0;cc<4;cc++){
        gtL0[cc] += uL_[4*g+cc]*d1L0;          gbL0[cc] += vR_[4*g+cc]*d2L0;
        gtL1[cc] += uL_[32+n1*8+ri1+cc]*d1L1;  gbL1[cc] += vR_[32+n1*8+ri1+cc]*d2L1;
      }
      #pragma unroll
      for (int cc=0;cc<2;cc++){
        gtL2[cc] += uL_[64+n2*8+ri2+cc]*d1L2;  gbL2[cc] += vR_[64+n2*8+ri2+cc]*d2L2;
      }
      gtL3 += uL_[80+g]*d1L3;  gbL3 += vR_[80+g]*d2L3;
    }
  }
  __syncthreads();

  { float* gr = &uvS[t*UVP];
    #pragma unroll
    for (int cc=0;cc<4;cc++){
      gr[4*g+cc] = gtL0[cc];                 gr[88+4*g+cc] = gbL0[cc];
      gr[32+n1*8+ri1+cc] = gtL1[cc];         gr[88+32+n1*8+ri1+cc] = gbL1[cc];
    }
    #pragma unroll
    for (int cc=0;cc<2;cc++){
      gr[64+n2*8+ri2+cc] = gtL2[cc];         gr[88+64+n2*8+ri2+cc] = gbL2[cc];
    }
    gr[80+g] = gtL3;  gr[88+80+g] = gbL3;
  }
  __syncthreads();

  den += __shfl_xor(den,1); den += __shfl_xor(den,2); den += __shfl_xor(den,4);
  float inv = 1.f / fmaxf(den, 1e-6f);
  const float* gr = &uvS[t*UVP];
  float yout[8];
  #pragma unroll
  for (int cc=0;cc<8;cc++){
    int j = g*8 + cc;
    float y = yacc[cc];
    if (cc<4){
      #pragma unroll
      for (int rr=0;rr<4;rr++) y += ULs[cc*4+rr]*gr[g*4+rr];
    } else {
      #pragma unroll
      for (int rr=0;rr<4;rr++) y += URs[(cc-4)*4+rr]*gr[88+g*4+rr];
    }
    { int seg=j>>4, pos=j&15;
      if (pos<8){
        #pragma unroll
        for (int rr=0;rr<8;rr++) y += ULs[16+pos*9+rr]*gr[32+seg*8+rr];
      } else {
        #pragma unroll
        for (int rr=0;rr<8;rr++) y += URs[16+(pos-8)*9+rr]*gr[88+32+seg*8+rr];
      } }
    { int seg=j>>5, pos=j&31;
      if (pos<16){
        #pragma unroll
        for (int rr=0;rr<8;rr++) y += ULs[88+pos*9+rr]*gr[64+seg*8+rr];
      } else {
        #pragma unroll
        for (int rr=0;rr<8;rr++) y += URs[88+(pos-16)*9+rr]*gr[88+64+seg*8+rr];
      } }
    { int pos=j;
      if (pos<32){
        #pragma unroll
        for (int rr=0;rr<8;rr++) y += ULs[232+pos*9+rr]*gr[80+rr];
      } else {
        #pragma unroll
        for (int rr=0;rr<8;rr++) y += URs[232+(pos-32)*9+rr]*gr[88+80+rr];
      } }
    yout[cc] = y*inv;
  }
  u16* yp = Yb + row*64 + g*8;
  ushort4 o1, o2;
  o1.x=f2b(yout[0]); o1.y=f2b(yout[1]); o1.z=f2b(yout[2]); o1.w=f2b(yout[3]);
  o2.x=f2b(yout[4]); o2.y=f2b(yout[5]); o2.z=f2b(yout[6]); o2.w=f2b(yout[7]);
  *(ushort4*)yp = o1;
  *(ushort4*)(yp+4) = o2;
}

// ---------------- Kernel 6: output projection — 8-way col split ----------------
__global__ __launch_bounds__(64,4) void k_outproj3(
    const u16* __restrict__ Yb, const u16* __restrict__ WoF, void* __restrict__ outv,
    const int* __restrict__ fl)
{
  const int f32 = fl[0];
  const int rows0 = blockIdx.x*32;
  const int nt0 = blockIdx.y*8;
  const int lane = threadIdx.x;
  const int quad = lane>>4, l16 = lane&15;

  f32x4 acc[16];
  #pragma unroll
  for (int i=0;i<16;i++) acc[i] = (f32x4){0.f,0.f,0.f,0.f};

  #pragma unroll
  for (int ks=0;ks<2;ks++){
    int ko = ks*32 + quad*8;
    bf16x8 a0 = *(const bf16x8*)(Yb + (size_t)(rows0 + l16)*DH_ + ko);
    bf16x8 a1 = *(const bf16x8*)(Yb + (size_t)(rows0 + 16 + l16)*DH_ + ko);
    #pragma unroll
    for (int nt=0;nt<8;nt++){
      bf16x8 b = *(const bf16x8*)(WoF + ((size_t)(ks*64 + nt0 + nt)*64 + lane)*8);
      acc[nt]   = __builtin_amdgcn_mfma_f32_16x16x32_bf16(a0,b,acc[nt],0,0,0);
      acc[8+nt] = __builtin_amdgcn_mfma_f32_16x16x32_bf16(a1,b,acc[8+nt],0,0,0);
    }
  }
  #pragma unroll
  for (int sp=0;sp<2;sp++){
    #pragma unroll
    for (int nt=0;nt<8;nt++){
      #pragma unroll
      for (int i=0;i<4;i++){
        int row = rows0 + sp*16 + quad*4 + i;
        int col = (nt0+nt)*16 + l16;
        size_t idx = (size_t)row*DM_ + col;
        float v = acc[sp*8+nt][i];
        if (f32) ((float*)outv)[idx] = v;
        else ((u16*)outv)[idx] = f2b(v);
      }
    }
  }
}

extern "C" void kernel_launch(void* const* d_in, const int* in_sizes, int n_in,
                              void* d_out, int out_size, void* d_ws, size_t ws_size,
                              hipStream_t stream) {
  const void* x  = d_in[0];
  const void* Wq = d_in[1];
  const void* Wk = d_in[2];
  const void* Wv = d_in[3];
  const void* Wo = d_in[4];
  const void* UL[4] = {d_in[5],d_in[6],d_in[7],d_in[8]};
  const void* VR[4] = {d_in[9],d_in[10],d_in[11],d_in[12]};
  const void* UR[4] = {d_in[13],d_in[14],d_in[15],d_in[16]};
  const void* VL[4] = {d_in[17],d_in[18],d_in[19],d_in[20]};

  int* flag = (int*)d_ws;
  float* ws = (float*)d_ws + 16;
  float* q    = ws;
  float* kf   = q    + (size_t)BT_*64;
  float* vf   = kf   + (size_t)BT_*64;
  float* uLa  = vf   + (size_t)BT_*64;
  float* vRa  = uLa  + (size_t)BT_*88;
  float* vrxa = vRa  + (size_t)BT_*88;
  float* vlxa = vrxa + (size_t)BT_*88;
  float* SL   = vlxa + (size_t)BT_*88;
  float* SP   = SL   + (size_t)B_*NCH_*STATE_;
  u16*   Yb   = (u16*)(SP + (size_t)B_*NCH_*STATE_);
  u16*   WF   = Yb  + (size_t)BT_*64;
  u16*   WoF  = WF  + (size_t)196608;
  u16*   PF   = WoF + (size_t)65536;
  u16*   qb16 = PF  + (size_t)18432;
  u16*   kb16 = qb16 + (size_t)BT_*64;
  u16*   vb16 = kb16 + (size_t)BT_*64;

  k_detect<<<1, 64, 0, stream>>>((const u16*)x, flag);
  k_wfrag<<<137, 256, 0, stream>>>(Wq, Wk, Wv, Wo,
      UL[0],UL[1],UL[2],UL[3], VR[0],VR[1],VR[2],VR[3], VL[0],VL[1],VL[2],VL[3],
      WF, WoF, PF, flag);
  k_proj8<<<BT_/64, 512, 0, stream>>>(x, WF, q, kf, vf, qb16, kb16, vb16, flag);
  k_prep3<<<dim3(BT_/16, 4), 64, 0, stream>>>(qb16, kb16, vb16, PF, uLa, vRa, vrxa, vlxa);
  k_chunksum<<<B_*NCH_, 256, 0, stream>>>(kf, vf, uLa, vRa, SL);
  k_prefix<<<dim3(B_, 4), 224, 0, stream>>>(SL, SP);
  k_intra<<<B_*NCH_, 128, 0, stream>>>(q, kf, vf, uLa, vRa, vrxa, vlxa, SP,
      UL[0],UL[1],UL[2],UL[3], UR[0],UR[1],UR[2],UR[3], Yb, flag);
  k_outproj3<<<dim3(512, 8), 64, 0, stream>>>(Yb, WoF, d_out, flag);
}